// Round 12
// baseline (278.735 us; speedup 1.0000x reference)
//
#include <hip/hip_runtime.h>
#include <hip/hip_bf16.h>

#define N_TOK 8192
#define C_DIM 512
#define NH 8
#define DH 64
#define KCLUST 4
#define TPF 512
#define TOPK 204
#define MPC 2048

// ---- workspace layout (float offsets) ----
#define WS_QHI    0            // q hi (pre-scaled 0.125): 4194304 shorts
#define WS_KHI    2097152
#define WS_VHI    4194304
#define WS_XAHI   6291456      // xattn hi
#define WS_XBARP  8388608      // 4*16*512
#define WS_QBAR   8421376      // 32*64
#define WS_G      8423424      // 4*512
#define WS_AGG    8425472      // 4*8192
#define WS_TOPK   8458240      // ints 4*204
#define WS_BAR    8459264      // ints: grid-barrier counters (8)

using frag16 = __attribute__((ext_vector_type(8))) short;
using f32x4  = __attribute__((ext_vector_type(4))) float;

__device__ __forceinline__ unsigned short f2bf(float x) {
  unsigned u = __float_as_uint(x);
  return (unsigned short)((u + 0x7fffu + ((u >> 16) & 1u)) >> 16);
}
__device__ __forceinline__ float bf2f(unsigned short h) {
  return __uint_as_float(((unsigned)h) << 16);
}
// packed RNE cvt of 2 floats -> 2 bf16 bit-patterns (v_cvt_pk_bf16_f32)
__device__ __forceinline__ unsigned pkbf(float a, float b) {
  __hip_bfloat162 t = __float22bfloat162_rn(make_float2(a, b));
  return *reinterpret_cast<unsigned*>(&t);
}

// ---------------------------------------------------------------------------
// QKV GEMM: 128x128 tile, 1-pass bf16; A = x fp32, B = w_qkv fp32, both cvt
// to bf16 in regs during staging. Reg-staged LDS dbuf, ONE barrier per
// K-iter, panel stride 1032 (bank skew), XCD swizzle, transpose epilogue.
// ---------------------------------------------------------------------------
#define APAN 1032
#define BUFS 8256  // 4*APAN (A) + 4*APAN (B)
__global__ __launch_bounds__(256) void gemm_qkv(
    const float* __restrict__ x, const float* __restrict__ w_qkv,
    const float* __restrict__ bias,
    unsigned short* __restrict__ qhi, unsigned short* __restrict__ khi,
    unsigned short* __restrict__ vhi) {
  __shared__ short pool[17408];  // loop: 2 x 8256 ; epilogue: 128 x 136
  const int tid = threadIdx.x;
  // swizzle: id = (m&7) + 8*jblk + 96*(m>>3); XCD = id%8 = m&7
  const int bid = blockIdx.x;
  const int grp = bid / 96;
  const int rem = bid - grp * 96;
  const int jblk = rem >> 3;
  const int m_idx = grp * 8 + (rem & 7);
  const int j0 = jblk * 128;
  const int m0 = m_idx * 128;
  const int wave = tid >> 6, lane = tid & 63;
  const int wr = wave >> 1, wc = wave & 1;
  const int qd = lane >> 4, ln = lane & 15;

  // staging: 512 (row,panel) units for A and B; 2 units/thread each
  const int r0 = tid >> 2, p0 = tid & 3;   // rows 0..63
  const int r1 = r0 + 64;                  // rows 64..127
  const float4* pA0 = reinterpret_cast<const float4*>(x + (size_t)(m0 + r0) * C_DIM) + p0 * 2;
  const float4* pA1 = reinterpret_cast<const float4*>(x + (size_t)(m0 + r1) * C_DIM) + p0 * 2;
  const float4* pB0 = reinterpret_cast<const float4*>(w_qkv + (size_t)(j0 + r0) * C_DIM) + p0 * 2;
  const float4* pB1 = reinterpret_cast<const float4*>(w_qkv + (size_t)(j0 + r1) * C_DIM) + p0 * 2;

  f32x4 acc[4][4] = {};

  float4 fa[4], fb[4];
  fa[0] = pA0[0]; fa[1] = pA0[1];
  fa[2] = pA1[0]; fa[3] = pA1[1];
  fb[0] = pB0[0]; fb[1] = pB0[1];
  fb[2] = pB1[0]; fb[3] = pB1[1];

  // prologue: cvt + write k-slab 0 into buf 0
  {
    *reinterpret_cast<uint4*>(&pool[p0 * APAN + r0 * 8]) =
        make_uint4(pkbf(fa[0].x, fa[0].y), pkbf(fa[0].z, fa[0].w),
                   pkbf(fa[1].x, fa[1].y), pkbf(fa[1].z, fa[1].w));
    *reinterpret_cast<uint4*>(&pool[p0 * APAN + r1 * 8]) =
        make_uint4(pkbf(fa[2].x, fa[2].y), pkbf(fa[2].z, fa[2].w),
                   pkbf(fa[3].x, fa[3].y), pkbf(fa[3].z, fa[3].w));
    *reinterpret_cast<uint4*>(&pool[4 * APAN + p0 * APAN + r0 * 8]) =
        make_uint4(pkbf(fb[0].x, fb[0].y), pkbf(fb[0].z, fb[0].w),
                   pkbf(fb[1].x, fb[1].y), pkbf(fb[1].z, fb[1].w));
    *reinterpret_cast<uint4*>(&pool[4 * APAN + p0 * APAN + r1 * 8]) =
        make_uint4(pkbf(fb[2].x, fb[2].y), pkbf(fb[2].z, fb[2].w),
                   pkbf(fb[3].x, fb[3].y), pkbf(fb[3].z, fb[3].w));
  }
  __syncthreads();

  int cur = 0;
#pragma unroll
  for (int it = 0; it < 16; it++) {
    if (it < 15) {  // issue next k-slab loads (latency hidden under MFMAs)
      int k4 = (it + 1) * 8;
      fa[0] = pA0[k4]; fa[1] = pA0[k4 + 1];
      fa[2] = pA1[k4]; fa[3] = pA1[k4 + 1];
      fb[0] = pB0[k4]; fb[1] = pB0[k4 + 1];
      fb[2] = pB1[k4]; fb[3] = pB1[k4 + 1];
    }
    const int bb = cur * BUFS;
    frag16 a_h[4], b_h[4];
#pragma unroll
    for (int i = 0; i < 4; i++) {
      int row = wr * 64 + i * 16 + ln;
      a_h[i] = *reinterpret_cast<const frag16*>(&pool[bb + qd * APAN + row * 8]);
    }
#pragma unroll
    for (int j = 0; j < 4; j++) {
      int row = wc * 64 + j * 16 + ln;
      b_h[j] = *reinterpret_cast<const frag16*>(&pool[bb + 4 * APAN + qd * APAN + row * 8]);
    }
#pragma unroll
    for (int i = 0; i < 4; i++)
#pragma unroll
      for (int j = 0; j < 4; j++)
        acc[i][j] = __builtin_amdgcn_mfma_f32_16x16x32_bf16(a_h[i], b_h[j], acc[i][j], 0, 0, 0);

    if (it < 15) {  // cvt + write next slab into the other buffer
      const int nb = (cur ^ 1) * BUFS;
      *reinterpret_cast<uint4*>(&pool[nb + p0 * APAN + r0 * 8]) =
          make_uint4(pkbf(fa[0].x, fa[0].y), pkbf(fa[0].z, fa[0].w),
                     pkbf(fa[1].x, fa[1].y), pkbf(fa[1].z, fa[1].w));
      *reinterpret_cast<uint4*>(&pool[nb + p0 * APAN + r1 * 8]) =
          make_uint4(pkbf(fa[2].x, fa[2].y), pkbf(fa[2].z, fa[2].w),
                     pkbf(fa[3].x, fa[3].y), pkbf(fa[3].z, fa[3].w));
      *reinterpret_cast<uint4*>(&pool[nb + 4 * APAN + p0 * APAN + r0 * 8]) =
          make_uint4(pkbf(fb[0].x, fb[0].y), pkbf(fb[0].z, fb[0].w),
                     pkbf(fb[1].x, fb[1].y), pkbf(fb[1].z, fb[1].w));
      *reinterpret_cast<uint4*>(&pool[nb + 4 * APAN + p0 * APAN + r1 * 8]) =
          make_uint4(pkbf(fb[2].x, fb[2].y), pkbf(fb[2].z, fb[2].w),
                     pkbf(fb[3].x, fb[3].y), pkbf(fb[3].z, fb[3].w));
    }
    __syncthreads();  // single barrier: flip buffers
    cur ^= 1;
  }

  // ---- epilogue: LDS transpose (128x136) -> coalesced line writes ----
  const int sel = j0 >> 9;
  const float qscale = (sel == 0) ? 0.125f : 1.0f;
  unsigned short* dst0 = (sel == 0) ? qhi : ((sel == 1) ? khi : vhi);
  short* sh = pool;

#pragma unroll
  for (int i = 0; i < 4; i++)
#pragma unroll
    for (int j = 0; j < 4; j++) {
      int jcol = wc * 64 + j * 16 + ln;
      float bv = bias[j0 + jcol];
#pragma unroll
      for (int r = 0; r < 4; r++) {
        int mrow = wr * 64 + i * 16 + qd * 4 + r;
        sh[mrow * 136 + jcol] = (short)f2bf((acc[i][j][r] + bv) * qscale);
      }
    }
  __syncthreads();
#pragma unroll
  for (int p = 0; p < 8; p++) {
    int u = tid + p * 256;
    int row = u >> 4, c = (u & 15) * 8;
    int hh = ((j0 + c) >> 6) & 7, d0 = c & 63;
    *reinterpret_cast<uint4*>(dst0 + ((size_t)hh * N_TOK + m0 + row) * DH + d0) =
        *reinterpret_cast<const uint4*>(&sh[row * 136 + c]);
  }
}

// ---------------------------------------------------------------------------
// Projection GEMM: 64x128, reg-dbuf pipeline (B = w_proj fp32 cvt in staging),
// swizzle, fp32 LDS-transpose epilogue.
// ---------------------------------------------------------------------------
__global__ __launch_bounds__(256) void gemm_proj(
    const unsigned short* __restrict__ Ahi, const float* __restrict__ w_proj,
    const float* __restrict__ bias, float* __restrict__ out) {
  __shared__ short pool[12288];
  short* As = pool;
  short* Bs = pool + 4096;
  const int tid = threadIdx.x;
  const int bid = blockIdx.x;
  const int grp = bid / 32;
  const int rem = bid - grp * 32;
  const int jblk = rem >> 3;
  const int m_idx = grp * 8 + (rem & 7);
  const int j0 = jblk * 128;
  const int m0 = m_idx * 64;
  const int wave = tid >> 6, lane = tid & 63;
  const int rh = wave >> 1, ch = wave & 1;
  const int qd = lane >> 4, ln = lane & 15;

  const int arow = tid & 63, ap = tid >> 6;
  const int brow = tid & 127, bp = tid >> 7;
  const unsigned short* pA = Ahi + (size_t)(m0 + arow) * C_DIM + ap * 8;
  const float4* pB0 = reinterpret_cast<const float4*>(w_proj + (size_t)(j0 + brow) * C_DIM) + bp * 2;
  const float4* pB1 = pB0 + 4;  // octet bp+2

  f32x4 acc[2][4] = {};

  uint4 ra = *reinterpret_cast<const uint4*>(pA);
  float4 f0a = pB0[0], f0b = pB0[1];
  float4 f1a = pB1[0], f1b = pB1[1];
  *reinterpret_cast<uint4*>(&As[ap * 512 + arow * 8]) = ra;
  *reinterpret_cast<uint4*>(&Bs[bp * 1024 + brow * 8]) =
      make_uint4(pkbf(f0a.x, f0a.y), pkbf(f0a.z, f0a.w), pkbf(f0b.x, f0b.y), pkbf(f0b.z, f0b.w));
  *reinterpret_cast<uint4*>(&Bs[(bp + 2) * 1024 + brow * 8]) =
      make_uint4(pkbf(f1a.x, f1a.y), pkbf(f1a.z, f1a.w), pkbf(f1b.x, f1b.y), pkbf(f1b.z, f1b.w));
  __syncthreads();

  int cur = 0;
#pragma unroll
  for (int it = 0; it < 16; it++) {
    if (it < 15) {
      int k = (it + 1) * 32;
      int k4 = (it + 1) * 8;
      ra = *reinterpret_cast<const uint4*>(pA + k);
      f0a = pB0[k4]; f0b = pB0[k4 + 1];
      f1a = pB1[k4]; f1b = pB1[k4 + 1];
    }
    frag16 a_h[2], b_h[4];
#pragma unroll
    for (int i = 0; i < 2; i++)
      a_h[i] = *reinterpret_cast<const frag16*>(&As[cur * 2048 + qd * 512 + (rh * 32 + i * 16 + ln) * 8]);
#pragma unroll
    for (int j = 0; j < 4; j++)
      b_h[j] = *reinterpret_cast<const frag16*>(&Bs[cur * 4096 + qd * 1024 + (ch * 64 + j * 16 + ln) * 8]);
#pragma unroll
    for (int i = 0; i < 2; i++)
#pragma unroll
      for (int j = 0; j < 4; j++)
        acc[i][j] = __builtin_amdgcn_mfma_f32_16x16x32_bf16(a_h[i], b_h[j], acc[i][j], 0, 0, 0);
    if (it < 15) {
      int nxt = cur ^ 1;
      *reinterpret_cast<uint4*>(&As[nxt * 2048 + ap * 512 + arow * 8]) = ra;
      *reinterpret_cast<uint4*>(&Bs[nxt * 4096 + bp * 1024 + brow * 8]) =
          make_uint4(pkbf(f0a.x, f0a.y), pkbf(f0a.z, f0a.w), pkbf(f0b.x, f0b.y), pkbf(f0b.z, f0b.w));
      *reinterpret_cast<uint4*>(&Bs[nxt * 4096 + (bp + 2) * 1024 + brow * 8]) =
          make_uint4(pkbf(f1a.x, f1a.y), pkbf(f1a.z, f1a.w), pkbf(f1b.x, f1b.y), pkbf(f1b.z, f1b.w));
      __syncthreads();
      cur = nxt;
    }
  }

  float* sh32 = reinterpret_cast<float*>(pool);  // 64 x 68
#pragma unroll
  for (int chp = 0; chp < 2; chp++) {
    __syncthreads();
    if (ch == chp) {
#pragma unroll
      for (int i = 0; i < 2; i++)
#pragma unroll
        for (int j = 0; j < 4; j++) {
          int jcol = j * 16 + ln;
          float bv = bias[j0 + chp * 64 + jcol];
#pragma unroll
          for (int r = 0; r < 4; r++)
            sh32[(rh * 32 + i * 16 + qd * 4 + r) * 68 + jcol] = acc[i][j][r] + bv;
        }
    }
    __syncthreads();
#pragma unroll
    for (int p = 0; p < 4; p++) {
      int u = tid + p * 256;
      int row = u >> 4, c4 = (u & 15) * 4;
      *reinterpret_cast<float4*>(out + (size_t)(m0 + row) * C_DIM + j0 + chp * 64 + c4) =
          *reinterpret_cast<const float4*>(&sh32[row * 68 + c4]);
    }
  }
}

// ---------------------------------------------------------------------------
// Fused fp32 ranking chain: xbarp -> qbar -> g -> agg -> topk in one kernel.
// 256 blocks (1024 waves, trivially all-resident on 256 CUs) with manual
// device-scope grid barriers (counters zeroed by hipMemsetAsync).
// ---------------------------------------------------------------------------
__device__ __forceinline__ void grid_barrier(int* cnt, int idx) {
  __syncthreads();
  if (threadIdx.x == 0) {
    __threadfence();
    atomicAdd(&cnt[idx], 1);
    while (atomicAdd(&cnt[idx], 0) < 256) __builtin_amdgcn_s_sleep(1);
    __threadfence();
  }
  __syncthreads();
}

__global__ __launch_bounds__(256) void rank_fused(
    const float* __restrict__ x, const float* __restrict__ w_qkv,
    const float* __restrict__ b_qkv, const int* __restrict__ keyframes,
    float* __restrict__ xbarp, float* __restrict__ qbar,
    float* __restrict__ g, float* __restrict__ agg,
    int* __restrict__ topk, int* __restrict__ bar) {
  __shared__ unsigned smem[8712];  // topk: sk 8192 | hist 256 | scn 256 | sel 2
  const int bid = blockIdx.x, tid = threadIdx.x;

  // ---- phase 0: xbar partials (64 units) ----
  if (bid < 64) {
    int kk = bid >> 4, s = bid & 15;
    int base = keyframes[kk] * TPF + s * 32;
    float a0 = 0.f, a1 = 0.f;
    for (int t = 0; t < 32; t++) {
      a0 += x[(size_t)(base + t) * C_DIM + tid];
      a1 += x[(size_t)(base + t) * C_DIM + tid + 256];
    }
    xbarp[(kk * 16 + s) * C_DIM + tid] = a0;
    xbarp[(kk * 16 + s) * C_DIM + tid + 256] = a1;
  }
  grid_barrier(bar, 0);

  // ---- phase 1: qbar (32 units) ----
  if (bid < 32) {
    float* xs = reinterpret_cast<float*>(smem);   // 512
    float* red = xs + C_DIM;                      // 256
    int h = bid >> 2, kk = bid & 3;
    for (int i = tid; i < C_DIM; i += 256) {
      float a = 0.f;
      for (int s = 0; s < 16; s++) a += xbarp[(kk * 16 + s) * C_DIM + i];
      xs[i] = a * (1.f / 512.f);
    }
    __syncthreads();
    int d = tid & 63, pp = tid >> 6;
    const float* wrow = w_qkv + (size_t)(h * 64 + d) * C_DIM + pp * 128;
    float a = 0.f;
    for (int c = 0; c < 128; c++) a += wrow[c] * xs[pp * 128 + c];
    red[tid] = a;
    __syncthreads();
    if (pp == 0)
      qbar[(h * 4 + kk) * 64 + d] = red[d] + red[64 + d] + red[128 + d] + red[192 + d] +
                                    b_qkv[h * 64 + d];
  }
  grid_barrier(bar, 1);

  // ---- phase 2: g (32 units) ----
  if (bid < 32) {
    float* qs = reinterpret_cast<float*>(smem);
    float* red = qs + C_DIM;
    int kk = bid >> 3, cs = bid & 7;
    for (int i = tid; i < C_DIM; i += 256)
      qs[i] = qbar[((i >> 6) * 4 + kk) * 64 + (i & 63)];
    __syncthreads();
    int jg = tid >> 6, c = tid & 63;
    float a = 0.f;
    const float* wk = w_qkv + (size_t)C_DIM * C_DIM + cs * 64 + c;
    for (int j = jg * 128; j < jg * 128 + 128; j++)
      a += qs[j] * wk[(size_t)j * C_DIM];
    red[tid] = a;
    __syncthreads();
    if (jg == 0)
      g[kk * C_DIM + cs * 64 + c] = red[c] + red[64 + c] + red[128 + c] + red[192 + c];
  }
  grid_barrier(bar, 2);

  // ---- phase 3: agg (2048 units, grid-stride) ----
  {
    float* gsm = reinterpret_cast<float*>(smem);  // 2048
    for (int i = tid; i < KCLUST * C_DIM; i += 256) gsm[i] = g[i];
    __syncthreads();
    int wave = tid >> 6, lane = tid & 63;
    for (int gg = bid; gg < 2048; gg += 256) {
      int n = gg * 4 + wave;
      const float4* xp = reinterpret_cast<const float4*>(x + (size_t)n * C_DIM);
      float4 xa = xp[lane], xb = xp[lane + 64];
      float a[4];
#pragma unroll
      for (int kk = 0; kk < 4; kk++) {
        const float4* gpv = reinterpret_cast<const float4*>(gsm + kk * C_DIM);
        float4 ga = gpv[lane], gb = gpv[lane + 64];
        a[kk] = xa.x * ga.x + xa.y * ga.y + xa.z * ga.z + xa.w * ga.w +
                xb.x * gb.x + xb.y * gb.y + xb.z * gb.z + xb.w * gb.w;
      }
#pragma unroll
      for (int off = 32; off >= 1; off >>= 1) {
        a[0] += __shfl_xor(a[0], off);
        a[1] += __shfl_xor(a[1], off);
        a[2] += __shfl_xor(a[2], off);
        a[3] += __shfl_xor(a[3], off);
      }
      if (lane == 0) {
        agg[0 * N_TOK + n] = a[0];
        agg[1 * N_TOK + n] = a[1];
        agg[2 * N_TOK + n] = a[2];
        agg[3 * N_TOK + n] = a[3];
      }
    }
  }
  grid_barrier(bar, 3);

  // ---- phase 4: top-204 radix select (4 units) ----
  if (bid < 4) {
    unsigned* sk = smem;
    int* hist = reinterpret_cast<int*>(smem + 8192);
    int* scn = hist + 256;
    int* selv = scn + 256;
    int kk = bid;
    const float* row = agg + (size_t)kk * N_TOK;

    __syncthreads();
    for (int i = tid; i < N_TOK; i += 256) {
      unsigned u = __float_as_uint(row[i]);
      sk[i] = (u & 0x80000000u) ? ~u : (u | 0x80000000u);
    }
    __syncthreads();

    unsigned prefix = 0;
    int remaining = TOPK;
#pragma unroll
    for (int rnd = 3; rnd >= 0; rnd--) {
      int shift = rnd * 8;
      hist[tid] = 0;
      __syncthreads();
      for (int i = tid; i < N_TOK; i += 256) {
        unsigned key = sk[i];
        bool in = (rnd == 3) || ((key >> (shift + 8)) == prefix);
        if (in) atomicAdd(&hist[(key >> shift) & 255], 1);
      }
      __syncthreads();
      scn[tid] = hist[255 - tid];
      __syncthreads();
      for (int s = 1; s < 256; s <<= 1) {
        int add = (tid >= s) ? scn[tid - s] : 0;
        __syncthreads();
        scn[tid] += add;
        __syncthreads();
      }
      int b = tid;
      int cgt = (b == 255) ? 0 : scn[254 - b];
      if (cgt < remaining && remaining <= cgt + hist[b]) {
        selv[0] = b;
        selv[1] = remaining - cgt;
      }
      __syncthreads();
      prefix = (prefix << 8) | (unsigned)selv[0];
      remaining = selv[1];
      __syncthreads();
    }
    unsigned kth = prefix;

    int* out_row = topk + kk * TOPK;
    int base = tid * 32;

    int cA = 0;
    for (int i = 0; i < 32; i++) cA += (sk[base + i] > kth) ? 1 : 0;
    scn[tid] = cA;
    __syncthreads();
    for (int s = 1; s < 256; s <<= 1) {
      int add = (tid >= s) ? scn[tid - s] : 0;
      __syncthreads();
      scn[tid] += add;
      __syncthreads();
    }
    int exclA = scn[tid] - cA;
    int G = scn[255];
    __syncthreads();
    int p = exclA;
    for (int i = 0; i < 32; i++)
      if (sk[base + i] > kth) out_row[p++] = base + i;
    __syncthreads();

    int cB = 0;
    for (int i = 0; i < 32; i++) cB += (sk[base + i] == kth) ? 1 : 0;
    scn[tid] = cB;
    __syncthreads();
    for (int s = 1; s < 256; s <<= 1) {
      int add = (tid >= s) ? scn[tid - s] : 0;
      __syncthreads();
      scn[tid] += add;
      __syncthreads();
    }
    int exclB = scn[tid] - cB;
    int pos = G + exclB;
    for (int i = 0; i < 32; i++) {
      if (sk[base + i] == kth) {
        if (pos < TOPK) out_row[pos] = base + i;
        pos++;
      }
    }
  }
}

// ---------------------------------------------------------------------------
// MFMA flash attention: 128 q/block, all hi-only, QK 1-pass, PV 1-pass.
// ---------------------------------------------------------------------------
__global__ __launch_bounds__(256) void flash_mfma(
    const unsigned short* __restrict__ qhi, const unsigned short* __restrict__ khi,
    const unsigned short* __restrict__ vhi, const int* __restrict__ topk,
    const int* __restrict__ clusters, unsigned short* __restrict__ xahi) {
  __shared__ short Ks[64 * 72];
  __shared__ short Vs[64 * 72];
  __shared__ short Ps[128 * 72];
  __shared__ int idx[TOPK];
  const int tid = threadIdx.x;
  const int qb = blockIdx.x, kk = blockIdx.y, h = blockIdx.z;
  const int wave = tid >> 6, lane = tid & 63;
  const int ln = lane & 15, qd = lane >> 4;

  for (int i = tid; i < TOPK; i += 256) idx[i] = topk[kk * TOPK + i];

  const int q_local0 = qb * 128;
  const int frame = clusters[kk * 4 + (q_local0 >> 9)];
  const int tokbase = frame * TPF + (q_local0 & 511);

  frag16 qa_h[2][2];
#pragma unroll
  for (int mt = 0; mt < 2; mt++) {
    const int tok_m = tokbase + wave * 32 + mt * 16 + ln;
    const unsigned short* qr_h = qhi + ((size_t)h * N_TOK + tok_m) * DH;
#pragma unroll
    for (int s = 0; s < 2; s++)
      qa_h[mt][s] = *reinterpret_cast<const frag16*>(qr_h + s * 32 + qd * 8);
  }

  f32x4 acc_o[2][4] = {};
  float lsum[2][4] = {};

  __syncthreads();

  for (int t0 = 0; t0 < TOPK; t0 += 64) {
#pragma unroll
    for (int i = 0; i < 2; i++) {
      int u = tid + i * 256;
      int r = u >> 3, oct = u & 7;
      int t = t0 + r;
      if (t > TOPK - 1) t = TOPK - 1;
      *reinterpret_cast<frag16*>(&Ks[r * 72 + oct * 8]) =
          *reinterpret_cast<const frag16*>(khi + ((size_t)h * N_TOK + idx[t]) * DH + oct * 8);
    }
    {
      int tk = (tid & 15) * 4, td = (tid >> 4) * 4;
      uint2 w2[4];
#pragma unroll
      for (int i = 0; i < 4; i++) {
        int t = t0 + tk + i;
        if (t > TOPK - 1) t = TOPK - 1;
        w2[i] = *reinterpret_cast<const uint2*>(vhi + ((size_t)h * N_TOK + idx[t]) * DH + td);
      }
#pragma unroll
      for (int dd = 0; dd < 4; dd++) {
        unsigned s0 = (dd < 2) ? (w2[0].x >> (16 * dd)) : (w2[0].y >> (16 * (dd - 2)));
        unsigned s1 = (dd < 2) ? (w2[1].x >> (16 * dd)) : (w2[1].y >> (16 * (dd - 2)));
        unsigned s2 = (dd < 2) ? (w2[2].x >> (16 * dd)) : (w2[2].y >> (16 * (dd - 2)));
        unsigned s3 = (dd < 2) ? (w2[3].x >> (16 * dd)) : (w2[3].y >> (16 * (dd - 2)));
        *reinterpret_cast<uint2*>(&Vs[(td + dd) * 72 + tk]) =
            make_uint2((s0 & 0xffffu) | (s1 << 16), (s2 & 0xffffu) | (s3 << 16));
      }
    }
    __syncthreads();

#pragma unroll
    for (int mt = 0; mt < 2; mt++) {
      f32x4 sacc[4] = {};
#pragma unroll
      for (int c = 0; c < 4; c++) {
#pragma unroll
        for (int s = 0; s < 2; s++) {
          frag16 bh = *reinterpret_cast<const frag16*>(&Ks[(c * 16 + ln) * 72 + s * 32 + qd * 8]);
          sacc[c] = __builtin_amdgcn_mfma_f32_16x16x32_bf16(qa_h[mt][s], bh, sacc[c], 0, 0, 0);
        }
      }
#pragma unroll
      for (int c = 0; c < 4; c++) {
#pragma unroll
        for (int r = 0; r < 4; r++) {
          int tg = t0 + c * 16 + ln;
          float p = (tg < TOPK) ? __expf(sacc[c][r]) : 0.f;
          lsum[mt][r] += p;
          Ps[(wave * 32 + mt * 16 + qd * 4 + r) * 72 + c * 16 + ln] = (short)f2bf(p);
        }
      }
    }

#pragma unroll
    for (int mt = 0; mt < 2; mt++)
#pragma unroll
      for (int s = 0; s < 2; s++) {
        frag16 pa = *reinterpret_cast<const frag16*>(
            &Ps[(wave * 32 + mt * 16 + ln) * 72 + s * 32 + qd * 8]);
#pragma unroll
        for (int dt = 0; dt < 4; dt++) {
          frag16 vb = *reinterpret_cast<const frag16*>(&Vs[(dt * 16 + ln) * 72 + s * 32 + qd * 8]);
          acc_o[mt][dt] = __builtin_amdgcn_mfma_f32_16x16x32_bf16(pa, vb, acc_o[mt][dt], 0, 0, 0);
        }
      }
    __syncthreads();
  }

#pragma unroll
  for (int mt = 0; mt < 2; mt++)
#pragma unroll
    for (int r = 0; r < 4; r++) {
      float l = lsum[mt][r];
      l += __shfl_xor(l, 1);
      l += __shfl_xor(l, 2);
      l += __shfl_xor(l, 4);
      l += __shfl_xor(l, 8);
      lsum[mt][r] = 1.f / l;
    }

#pragma unroll
  for (int mt = 0; mt < 2; mt++)
#pragma unroll
    for (int dt = 0; dt < 4; dt++)
#pragma unroll
      for (int r = 0; r < 4; r++)
        Ps[(wave * 32 + mt * 16 + qd * 4 + r) * 72 + dt * 16 + ln] =
            (short)f2bf(acc_o[mt][dt][r] * lsum[mt][r]);
  __syncthreads();
#pragma unroll
  for (int p = 0; p < 4; p++) {
    int u = tid + p * 256;
    int row = u >> 3, c = (u & 7) * 8;
    *reinterpret_cast<uint4*>(xahi + (size_t)(tokbase + row) * C_DIM + h * DH + c) =
        *reinterpret_cast<const uint4*>(&Ps[row * 72 + c]);
  }
}

// ---------------------------------------------------------------------------
extern "C" void kernel_launch(void* const* d_in, const int* in_sizes, int n_in,
                              void* d_out, int out_size, void* d_ws, size_t ws_size,
                              hipStream_t stream) {
  const float* x = (const float*)d_in[0];
  const float* w_qkv = (const float*)d_in[1];
  const float* b_qkv = (const float*)d_in[2];
  const float* w_proj = (const float*)d_in[3];
  const float* b_proj = (const float*)d_in[4];
  const int* keyframes = (const int*)d_in[5];
  const int* clusters = (const int*)d_in[6];
  float* out = (float*)d_out;
  float* ws = (float*)d_ws;

  unsigned short* qhi = (unsigned short*)(ws + WS_QHI);
  unsigned short* khi = (unsigned short*)(ws + WS_KHI);
  unsigned short* vhi = (unsigned short*)(ws + WS_VHI);
  unsigned short* xahi = (unsigned short*)(ws + WS_XAHI);
  float* xbarp = ws + WS_XBARP;
  float* qbar = ws + WS_QBAR;
  float* g = ws + WS_G;
  float* agg = ws + WS_AGG;
  int* topkp = (int*)(ws + WS_TOPK);
  int* bar = (int*)(ws + WS_BAR);

  // 0. zero grid-barrier counters (graph-capturable async memset)
  hipMemsetAsync(bar, 0, 8 * sizeof(int), stream);
  // 1. QKV GEMM (reads x, w_qkv fp32 directly; cvt in staging)
  gemm_qkv<<<768, 256, 0, stream>>>(x, w_qkv, b_qkv, qhi, khi, vhi);
  // 2. fused fp32 ranking chain -> topk
  rank_fused<<<256, 256, 0, stream>>>(x, w_qkv, b_qkv, keyframes, xbarp,
                                      qbar, g, agg, topkp, bar);
  // 3. fused MFMA attention
  flash_mfma<<<dim3(MPC / 128, KCLUST, NH), 256, 0, stream>>>(
      qhi, khi, vhi, topkp, clusters, xahi);
  // 4. projection GEMM (reads w_proj fp32 directly)
  gemm_proj<<<512, 256, 0, stream>>>(xahi, w_proj, b_proj, out);
}

// Round 13
// 277.637 us; speedup vs baseline: 1.0040x; 1.0040x over previous
//
#include <hip/hip_runtime.h>
#include <hip/hip_bf16.h>

#define N_TOK 8192
#define C_DIM 512
#define NH 8
#define DH 64
#define KCLUST 4
#define TPF 512
#define TOPK 204
#define MPC 2048

// ---- workspace layout (float offsets) ----
#define WS_QHI    0            // q hi (pre-scaled 0.125): 4194304 shorts
#define WS_KHI    2097152
#define WS_VHI    4194304
#define WS_XAHI   6291456      // xattn hi
#define WS_XBARP  8388608      // 4*16*512
#define WS_QBAR   8421376      // 32*64
#define WS_G      8423424      // 4*512
#define WS_AGG    8425472      // 4*8192
#define WS_TOPK   8458240      // ints 4*204
#define WS_BAR    8459264      // ints: grid-barrier counters (8)

using frag16 = __attribute__((ext_vector_type(8))) short;
using f32x4  = __attribute__((ext_vector_type(4))) float;

__device__ __forceinline__ unsigned short f2bf(float x) {
  unsigned u = __float_as_uint(x);
  return (unsigned short)((u + 0x7fffu + ((u >> 16) & 1u)) >> 16);
}
__device__ __forceinline__ float bf2f(unsigned short h) {
  return __uint_as_float(((unsigned)h) << 16);
}
// packed RNE cvt of 2 floats -> 2 bf16 bit-patterns (v_cvt_pk_bf16_f32)
__device__ __forceinline__ unsigned pkbf(float a, float b) {
  __hip_bfloat162 t = __float22bfloat162_rn(make_float2(a, b));
  return *reinterpret_cast<unsigned*>(&t);
}

// ---------------------------------------------------------------------------
// QKV GEMM: 128x128 tile, 1-pass bf16; A = x fp32, B = w_qkv fp32, both cvt
// to bf16 in regs during staging. Reg-staged LDS dbuf, ONE barrier per
// K-iter, panel stride 1032 (bank skew), XCD swizzle, transpose epilogue.
// ---------------------------------------------------------------------------
#define APAN 1032
#define BUFS 8256  // 4*APAN (A) + 4*APAN (B)
__global__ __launch_bounds__(256) void gemm_qkv(
    const float* __restrict__ x, const float* __restrict__ w_qkv,
    const float* __restrict__ bias,
    unsigned short* __restrict__ qhi, unsigned short* __restrict__ khi,
    unsigned short* __restrict__ vhi) {
  __shared__ short pool[17408];  // loop: 2 x 8256 ; epilogue: 128 x 136
  const int tid = threadIdx.x;
  // swizzle: id = (m&7) + 8*jblk + 96*(m>>3); XCD = id%8 = m&7
  const int bid = blockIdx.x;
  const int grp = bid / 96;
  const int rem = bid - grp * 96;
  const int jblk = rem >> 3;
  const int m_idx = grp * 8 + (rem & 7);
  const int j0 = jblk * 128;
  const int m0 = m_idx * 128;
  const int wave = tid >> 6, lane = tid & 63;
  const int wr = wave >> 1, wc = wave & 1;
  const int qd = lane >> 4, ln = lane & 15;

  // staging: 512 (row,panel) units for A and B; 2 units/thread each
  const int r0 = tid >> 2, p0 = tid & 3;   // rows 0..63
  const int r1 = r0 + 64;                  // rows 64..127
  const float4* pA0 = reinterpret_cast<const float4*>(x + (size_t)(m0 + r0) * C_DIM) + p0 * 2;
  const float4* pA1 = reinterpret_cast<const float4*>(x + (size_t)(m0 + r1) * C_DIM) + p0 * 2;
  const float4* pB0 = reinterpret_cast<const float4*>(w_qkv + (size_t)(j0 + r0) * C_DIM) + p0 * 2;
  const float4* pB1 = reinterpret_cast<const float4*>(w_qkv + (size_t)(j0 + r1) * C_DIM) + p0 * 2;

  f32x4 acc[4][4] = {};

  float4 fa[4], fb[4];
  fa[0] = pA0[0]; fa[1] = pA0[1];
  fa[2] = pA1[0]; fa[3] = pA1[1];
  fb[0] = pB0[0]; fb[1] = pB0[1];
  fb[2] = pB1[0]; fb[3] = pB1[1];

  // prologue: cvt + write k-slab 0 into buf 0
  {
    *reinterpret_cast<uint4*>(&pool[p0 * APAN + r0 * 8]) =
        make_uint4(pkbf(fa[0].x, fa[0].y), pkbf(fa[0].z, fa[0].w),
                   pkbf(fa[1].x, fa[1].y), pkbf(fa[1].z, fa[1].w));
    *reinterpret_cast<uint4*>(&pool[p0 * APAN + r1 * 8]) =
        make_uint4(pkbf(fa[2].x, fa[2].y), pkbf(fa[2].z, fa[2].w),
                   pkbf(fa[3].x, fa[3].y), pkbf(fa[3].z, fa[3].w));
    *reinterpret_cast<uint4*>(&pool[4 * APAN + p0 * APAN + r0 * 8]) =
        make_uint4(pkbf(fb[0].x, fb[0].y), pkbf(fb[0].z, fb[0].w),
                   pkbf(fb[1].x, fb[1].y), pkbf(fb[1].z, fb[1].w));
    *reinterpret_cast<uint4*>(&pool[4 * APAN + p0 * APAN + r1 * 8]) =
        make_uint4(pkbf(fb[2].x, fb[2].y), pkbf(fb[2].z, fb[2].w),
                   pkbf(fb[3].x, fb[3].y), pkbf(fb[3].z, fb[3].w));
  }
  __syncthreads();

  int cur = 0;
#pragma unroll
  for (int it = 0; it < 16; it++) {
    if (it < 15) {  // issue next k-slab loads (latency hidden under MFMAs)
      int k4 = (it + 1) * 8;
      fa[0] = pA0[k4]; fa[1] = pA0[k4 + 1];
      fa[2] = pA1[k4]; fa[3] = pA1[k4 + 1];
      fb[0] = pB0[k4]; fb[1] = pB0[k4 + 1];
      fb[2] = pB1[k4]; fb[3] = pB1[k4 + 1];
    }
    const int bb = cur * BUFS;
    frag16 a_h[4], b_h[4];
#pragma unroll
    for (int i = 0; i < 4; i++) {
      int row = wr * 64 + i * 16 + ln;
      a_h[i] = *reinterpret_cast<const frag16*>(&pool[bb + qd * APAN + row * 8]);
    }
#pragma unroll
    for (int j = 0; j < 4; j++) {
      int row = wc * 64 + j * 16 + ln;
      b_h[j] = *reinterpret_cast<const frag16*>(&pool[bb + 4 * APAN + qd * APAN + row * 8]);
    }
#pragma unroll
    for (int i = 0; i < 4; i++)
#pragma unroll
      for (int j = 0; j < 4; j++)
        acc[i][j] = __builtin_amdgcn_mfma_f32_16x16x32_bf16(a_h[i], b_h[j], acc[i][j], 0, 0, 0);

    if (it < 15) {  // cvt + write next slab into the other buffer
      const int nb = (cur ^ 1) * BUFS;
      *reinterpret_cast<uint4*>(&pool[nb + p0 * APAN + r0 * 8]) =
          make_uint4(pkbf(fa[0].x, fa[0].y), pkbf(fa[0].z, fa[0].w),
                     pkbf(fa[1].x, fa[1].y), pkbf(fa[1].z, fa[1].w));
      *reinterpret_cast<uint4*>(&pool[nb + p0 * APAN + r1 * 8]) =
          make_uint4(pkbf(fa[2].x, fa[2].y), pkbf(fa[2].z, fa[2].w),
                     pkbf(fa[3].x, fa[3].y), pkbf(fa[3].z, fa[3].w));
      *reinterpret_cast<uint4*>(&pool[nb + 4 * APAN + p0 * APAN + r0 * 8]) =
          make_uint4(pkbf(fb[0].x, fb[0].y), pkbf(fb[0].z, fb[0].w),
                     pkbf(fb[1].x, fb[1].y), pkbf(fb[1].z, fb[1].w));
      *reinterpret_cast<uint4*>(&pool[nb + 4 * APAN + p0 * APAN + r1 * 8]) =
          make_uint4(pkbf(fb[2].x, fb[2].y), pkbf(fb[2].z, fb[2].w),
                     pkbf(fb[3].x, fb[3].y), pkbf(fb[3].z, fb[3].w));
    }
    __syncthreads();  // single barrier: flip buffers
    cur ^= 1;
  }

  // ---- epilogue: LDS transpose (128x136) -> coalesced line writes ----
  const int sel = j0 >> 9;
  const float qscale = (sel == 0) ? 0.125f : 1.0f;
  unsigned short* dst0 = (sel == 0) ? qhi : ((sel == 1) ? khi : vhi);
  short* sh = pool;

#pragma unroll
  for (int i = 0; i < 4; i++)
#pragma unroll
    for (int j = 0; j < 4; j++) {
      int jcol = wc * 64 + j * 16 + ln;
      float bv = bias[j0 + jcol];
#pragma unroll
      for (int r = 0; r < 4; r++) {
        int mrow = wr * 64 + i * 16 + qd * 4 + r;
        sh[mrow * 136 + jcol] = (short)f2bf((acc[i][j][r] + bv) * qscale);
      }
    }
  __syncthreads();
#pragma unroll
  for (int p = 0; p < 8; p++) {
    int u = tid + p * 256;
    int row = u >> 4, c = (u & 15) * 8;
    int hh = ((j0 + c) >> 6) & 7, d0 = c & 63;
    *reinterpret_cast<uint4*>(dst0 + ((size_t)hh * N_TOK + m0 + row) * DH + d0) =
        *reinterpret_cast<const uint4*>(&sh[row * 136 + c]);
  }
}

// ---------------------------------------------------------------------------
// Projection GEMM: 64x128, reg-dbuf pipeline (B = w_proj fp32 cvt in staging),
// swizzle, fp32 LDS-transpose epilogue.
// ---------------------------------------------------------------------------
__global__ __launch_bounds__(256) void gemm_proj(
    const unsigned short* __restrict__ Ahi, const float* __restrict__ w_proj,
    const float* __restrict__ bias, float* __restrict__ out) {
  __shared__ short pool[12288];
  short* As = pool;
  short* Bs = pool + 4096;
  const int tid = threadIdx.x;
  const int bid = blockIdx.x;
  const int grp = bid / 32;
  const int rem = bid - grp * 32;
  const int jblk = rem >> 3;
  const int m_idx = grp * 8 + (rem & 7);
  const int j0 = jblk * 128;
  const int m0 = m_idx * 64;
  const int wave = tid >> 6, lane = tid & 63;
  const int rh = wave >> 1, ch = wave & 1;
  const int qd = lane >> 4, ln = lane & 15;

  const int arow = tid & 63, ap = tid >> 6;
  const int brow = tid & 127, bp = tid >> 7;
  const unsigned short* pA = Ahi + (size_t)(m0 + arow) * C_DIM + ap * 8;
  const float4* pB0 = reinterpret_cast<const float4*>(w_proj + (size_t)(j0 + brow) * C_DIM) + bp * 2;
  const float4* pB1 = pB0 + 4;  // octet bp+2

  f32x4 acc[2][4] = {};

  uint4 ra = *reinterpret_cast<const uint4*>(pA);
  float4 f0a = pB0[0], f0b = pB0[1];
  float4 f1a = pB1[0], f1b = pB1[1];
  *reinterpret_cast<uint4*>(&As[ap * 512 + arow * 8]) = ra;
  *reinterpret_cast<uint4*>(&Bs[bp * 1024 + brow * 8]) =
      make_uint4(pkbf(f0a.x, f0a.y), pkbf(f0a.z, f0a.w), pkbf(f0b.x, f0b.y), pkbf(f0b.z, f0b.w));
  *reinterpret_cast<uint4*>(&Bs[(bp + 2) * 1024 + brow * 8]) =
      make_uint4(pkbf(f1a.x, f1a.y), pkbf(f1a.z, f1a.w), pkbf(f1b.x, f1b.y), pkbf(f1b.z, f1b.w));
  __syncthreads();

  int cur = 0;
#pragma unroll
  for (int it = 0; it < 16; it++) {
    if (it < 15) {
      int k = (it + 1) * 32;
      int k4 = (it + 1) * 8;
      ra = *reinterpret_cast<const uint4*>(pA + k);
      f0a = pB0[k4]; f0b = pB0[k4 + 1];
      f1a = pB1[k4]; f1b = pB1[k4 + 1];
    }
    frag16 a_h[2], b_h[4];
#pragma unroll
    for (int i = 0; i < 2; i++)
      a_h[i] = *reinterpret_cast<const frag16*>(&As[cur * 2048 + qd * 512 + (rh * 32 + i * 16 + ln) * 8]);
#pragma unroll
    for (int j = 0; j < 4; j++)
      b_h[j] = *reinterpret_cast<const frag16*>(&Bs[cur * 4096 + qd * 1024 + (ch * 64 + j * 16 + ln) * 8]);
#pragma unroll
    for (int i = 0; i < 2; i++)
#pragma unroll
      for (int j = 0; j < 4; j++)
        acc[i][j] = __builtin_amdgcn_mfma_f32_16x16x32_bf16(a_h[i], b_h[j], acc[i][j], 0, 0, 0);
    if (it < 15) {
      int nxt = cur ^ 1;
      *reinterpret_cast<uint4*>(&As[nxt * 2048 + ap * 512 + arow * 8]) = ra;
      *reinterpret_cast<uint4*>(&Bs[nxt * 4096 + bp * 1024 + brow * 8]) =
          make_uint4(pkbf(f0a.x, f0a.y), pkbf(f0a.z, f0a.w), pkbf(f0b.x, f0b.y), pkbf(f0b.z, f0b.w));
      *reinterpret_cast<uint4*>(&Bs[nxt * 4096 + (bp + 2) * 1024 + brow * 8]) =
          make_uint4(pkbf(f1a.x, f1a.y), pkbf(f1a.z, f1a.w), pkbf(f1b.x, f1b.y), pkbf(f1b.z, f1b.w));
      __syncthreads();
      cur = nxt;
    }
  }

  float* sh32 = reinterpret_cast<float*>(pool);  // 64 x 68
#pragma unroll
  for (int chp = 0; chp < 2; chp++) {
    __syncthreads();
    if (ch == chp) {
#pragma unroll
      for (int i = 0; i < 2; i++)
#pragma unroll
        for (int j = 0; j < 4; j++) {
          int jcol = j * 16 + ln;
          float bv = bias[j0 + chp * 64 + jcol];
#pragma unroll
          for (int r = 0; r < 4; r++)
            sh32[(rh * 32 + i * 16 + qd * 4 + r) * 68 + jcol] = acc[i][j][r] + bv;
        }
    }
    __syncthreads();
#pragma unroll
    for (int p = 0; p < 4; p++) {
      int u = tid + p * 256;
      int row = u >> 4, c4 = (u & 15) * 4;
      *reinterpret_cast<float4*>(out + (size_t)(m0 + row) * C_DIM + j0 + chp * 64 + c4) =
          *reinterpret_cast<const float4*>(&sh32[row * 68 + c4]);
    }
  }
}

// ---------------------------------------------------------------------------
// Fused fp32 ranking chain: xbarp -> qbar -> g -> agg -> topk in one kernel.
// 256 blocks (deadlock-free by resources: 35 KB LDS -> 4 blocks/CU, so all
// 256 blocks are resident regardless of placement). Grid barrier: one RMW
// arrival per block + relaxed agent-scope LOAD polling (no RMW storm).
// ---------------------------------------------------------------------------
__device__ __forceinline__ void grid_barrier(int* cnt, int idx) {
  __syncthreads();
  if (threadIdx.x == 0) {
    __threadfence();
    atomicAdd(&cnt[idx], 1);
    while (__hip_atomic_load(&cnt[idx], __ATOMIC_RELAXED,
                             __HIP_MEMORY_SCOPE_AGENT) < 256)
      __builtin_amdgcn_s_sleep(2);
    __threadfence();
  }
  __syncthreads();
}

__global__ __launch_bounds__(256) void rank_fused(
    const float* __restrict__ x, const float* __restrict__ w_qkv,
    const float* __restrict__ b_qkv, const int* __restrict__ keyframes,
    float* __restrict__ xbarp, float* __restrict__ qbar,
    float* __restrict__ g, float* __restrict__ agg,
    int* __restrict__ topk, int* __restrict__ bar) {
  __shared__ unsigned smem[8712];  // topk: sk 8192 | hist 256 | scn 256 | sel 2
  const int bid = blockIdx.x, tid = threadIdx.x;

  // ---- phase 0: xbar partials (64 units) ----
  if (bid < 64) {
    int kk = bid >> 4, s = bid & 15;
    int base = keyframes[kk] * TPF + s * 32;
    float a0 = 0.f, a1 = 0.f;
    for (int t = 0; t < 32; t++) {
      a0 += x[(size_t)(base + t) * C_DIM + tid];
      a1 += x[(size_t)(base + t) * C_DIM + tid + 256];
    }
    xbarp[(kk * 16 + s) * C_DIM + tid] = a0;
    xbarp[(kk * 16 + s) * C_DIM + tid + 256] = a1;
  }
  grid_barrier(bar, 0);

  // ---- phase 1: qbar (32 units) ----
  if (bid < 32) {
    float* xs = reinterpret_cast<float*>(smem);   // 512
    float* red = xs + C_DIM;                      // 256
    int h = bid >> 2, kk = bid & 3;
    for (int i = tid; i < C_DIM; i += 256) {
      float a = 0.f;
      for (int s = 0; s < 16; s++) a += xbarp[(kk * 16 + s) * C_DIM + i];
      xs[i] = a * (1.f / 512.f);
    }
    __syncthreads();
    int d = tid & 63, pp = tid >> 6;
    const float* wrow = w_qkv + (size_t)(h * 64 + d) * C_DIM + pp * 128;
    float a = 0.f;
    for (int c = 0; c < 128; c++) a += wrow[c] * xs[pp * 128 + c];
    red[tid] = a;
    __syncthreads();
    if (pp == 0)
      qbar[(h * 4 + kk) * 64 + d] = red[d] + red[64 + d] + red[128 + d] + red[192 + d] +
                                    b_qkv[h * 64 + d];
  }
  grid_barrier(bar, 1);

  // ---- phase 2: g (32 units) ----
  if (bid < 32) {
    float* qs = reinterpret_cast<float*>(smem);
    float* red = qs + C_DIM;
    int kk = bid >> 3, cs = bid & 7;
    for (int i = tid; i < C_DIM; i += 256)
      qs[i] = qbar[((i >> 6) * 4 + kk) * 64 + (i & 63)];
    __syncthreads();
    int jg = tid >> 6, c = tid & 63;
    float a = 0.f;
    const float* wk = w_qkv + (size_t)C_DIM * C_DIM + cs * 64 + c;
    for (int j = jg * 128; j < jg * 128 + 128; j++)
      a += qs[j] * wk[(size_t)j * C_DIM];
    red[tid] = a;
    __syncthreads();
    if (jg == 0)
      g[kk * C_DIM + cs * 64 + c] = red[c] + red[64 + c] + red[128 + c] + red[192 + c];
  }
  grid_barrier(bar, 2);

  // ---- phase 3: agg (2048 units, grid-stride) ----
  {
    float* gsm = reinterpret_cast<float*>(smem);  // 2048
    for (int i = tid; i < KCLUST * C_DIM; i += 256) gsm[i] = g[i];
    __syncthreads();
    int wave = tid >> 6, lane = tid & 63;
    for (int gg = bid; gg < 2048; gg += 256) {
      int n = gg * 4 + wave;
      const float4* xp = reinterpret_cast<const float4*>(x + (size_t)n * C_DIM);
      float4 xa = xp[lane], xb = xp[lane + 64];
      float a[4];
#pragma unroll
      for (int kk = 0; kk < 4; kk++) {
        const float4* gpv = reinterpret_cast<const float4*>(gsm + kk * C_DIM);
        float4 ga = gpv[lane], gb = gpv[lane + 64];
        a[kk] = xa.x * ga.x + xa.y * ga.y + xa.z * ga.z + xa.w * ga.w +
                xb.x * gb.x + xb.y * gb.y + xb.z * gb.z + xb.w * gb.w;
      }
#pragma unroll
      for (int off = 32; off >= 1; off >>= 1) {
        a[0] += __shfl_xor(a[0], off);
        a[1] += __shfl_xor(a[1], off);
        a[2] += __shfl_xor(a[2], off);
        a[3] += __shfl_xor(a[3], off);
      }
      if (lane == 0) {
        agg[0 * N_TOK + n] = a[0];
        agg[1 * N_TOK + n] = a[1];
        agg[2 * N_TOK + n] = a[2];
        agg[3 * N_TOK + n] = a[3];
      }
    }
  }
  grid_barrier(bar, 3);

  // ---- phase 4: top-204 radix select (4 units) ----
  if (bid < 4) {
    unsigned* sk = smem;
    int* hist = reinterpret_cast<int*>(smem + 8192);
    int* scn = hist + 256;
    int* selv = scn + 256;
    int kk = bid;
    const float* row = agg + (size_t)kk * N_TOK;

    __syncthreads();
    for (int i = tid; i < N_TOK; i += 256) {
      unsigned u = __float_as_uint(row[i]);
      sk[i] = (u & 0x80000000u) ? ~u : (u | 0x80000000u);
    }
    __syncthreads();

    unsigned prefix = 0;
    int remaining = TOPK;
#pragma unroll
    for (int rnd = 3; rnd >= 0; rnd--) {
      int shift = rnd * 8;
      hist[tid] = 0;
      __syncthreads();
      for (int i = tid; i < N_TOK; i += 256) {
        unsigned key = sk[i];
        bool in = (rnd == 3) || ((key >> (shift + 8)) == prefix);
        if (in) atomicAdd(&hist[(key >> shift) & 255], 1);
      }
      __syncthreads();
      scn[tid] = hist[255 - tid];
      __syncthreads();
      for (int s = 1; s < 256; s <<= 1) {
        int add = (tid >= s) ? scn[tid - s] : 0;
        __syncthreads();
        scn[tid] += add;
        __syncthreads();
      }
      int b = tid;
      int cgt = (b == 255) ? 0 : scn[254 - b];
      if (cgt < remaining && remaining <= cgt + hist[b]) {
        selv[0] = b;
        selv[1] = remaining - cgt;
      }
      __syncthreads();
      prefix = (prefix << 8) | (unsigned)selv[0];
      remaining = selv[1];
      __syncthreads();
    }
    unsigned kth = prefix;

    int* out_row = topk + kk * TOPK;
    int base = tid * 32;

    int cA = 0;
    for (int i = 0; i < 32; i++) cA += (sk[base + i] > kth) ? 1 : 0;
    scn[tid] = cA;
    __syncthreads();
    for (int s = 1; s < 256; s <<= 1) {
      int add = (tid >= s) ? scn[tid - s] : 0;
      __syncthreads();
      scn[tid] += add;
      __syncthreads();
    }
    int exclA = scn[tid] - cA;
    int G = scn[255];
    __syncthreads();
    int p = exclA;
    for (int i = 0; i < 32; i++)
      if (sk[base + i] > kth) out_row[p++] = base + i;
    __syncthreads();

    int cB = 0;
    for (int i = 0; i < 32; i++) cB += (sk[base + i] == kth) ? 1 : 0;
    scn[tid] = cB;
    __syncthreads();
    for (int s = 1; s < 256; s <<= 1) {
      int add = (tid >= s) ? scn[tid - s] : 0;
      __syncthreads();
      scn[tid] += add;
      __syncthreads();
    }
    int exclB = scn[tid] - cB;
    int pos = G + exclB;
    for (int i = 0; i < 32; i++) {
      if (sk[base + i] == kth) {
        if (pos < TOPK) out_row[pos] = base + i;
        pos++;
      }
    }
  }
}

// ---------------------------------------------------------------------------
// MFMA flash attention: 128 q/block, all hi-only, QK 1-pass, PV 1-pass.
// ---------------------------------------------------------------------------
__global__ __launch_bounds__(256) void flash_mfma(
    const unsigned short* __restrict__ qhi, const unsigned short* __restrict__ khi,
    const unsigned short* __restrict__ vhi, const int* __restrict__ topk,
    const int* __restrict__ clusters, unsigned short* __restrict__ xahi) {
  __shared__ short Ks[64 * 72];
  __shared__ short Vs[64 * 72];
  __shared__ short Ps[128 * 72];
  __shared__ int idx[TOPK];
  const int tid = threadIdx.x;
  const int qb = blockIdx.x, kk = blockIdx.y, h = blockIdx.z;
  const int wave = tid >> 6, lane = tid & 63;
  const int ln = lane & 15, qd = lane >> 4;

  for (int i = tid; i < TOPK; i += 256) idx[i] = topk[kk * TOPK + i];

  const int q_local0 = qb * 128;
  const int frame = clusters[kk * 4 + (q_local0 >> 9)];
  const int tokbase = frame * TPF + (q_local0 & 511);

  frag16 qa_h[2][2];
#pragma unroll
  for (int mt = 0; mt < 2; mt++) {
    const int tok_m = tokbase + wave * 32 + mt * 16 + ln;
    const unsigned short* qr_h = qhi + ((size_t)h * N_TOK + tok_m) * DH;
#pragma unroll
    for (int s = 0; s < 2; s++)
      qa_h[mt][s] = *reinterpret_cast<const frag16*>(qr_h + s * 32 + qd * 8);
  }

  f32x4 acc_o[2][4] = {};
  float lsum[2][4] = {};

  __syncthreads();

  for (int t0 = 0; t0 < TOPK; t0 += 64) {
#pragma unroll
    for (int i = 0; i < 2; i++) {
      int u = tid + i * 256;
      int r = u >> 3, oct = u & 7;
      int t = t0 + r;
      if (t > TOPK - 1) t = TOPK - 1;
      *reinterpret_cast<frag16*>(&Ks[r * 72 + oct * 8]) =
          *reinterpret_cast<const frag16*>(khi + ((size_t)h * N_TOK + idx[t]) * DH + oct * 8);
    }
    {
      int tk = (tid & 15) * 4, td = (tid >> 4) * 4;
      uint2 w2[4];
#pragma unroll
      for (int i = 0; i < 4; i++) {
        int t = t0 + tk + i;
        if (t > TOPK - 1) t = TOPK - 1;
        w2[i] = *reinterpret_cast<const uint2*>(vhi + ((size_t)h * N_TOK + idx[t]) * DH + td);
      }
#pragma unroll
      for (int dd = 0; dd < 4; dd++) {
        unsigned s0 = (dd < 2) ? (w2[0].x >> (16 * dd)) : (w2[0].y >> (16 * (dd - 2)));
        unsigned s1 = (dd < 2) ? (w2[1].x >> (16 * dd)) : (w2[1].y >> (16 * (dd - 2)));
        unsigned s2 = (dd < 2) ? (w2[2].x >> (16 * dd)) : (w2[2].y >> (16 * (dd - 2)));
        unsigned s3 = (dd < 2) ? (w2[3].x >> (16 * dd)) : (w2[3].y >> (16 * (dd - 2)));
        *reinterpret_cast<uint2*>(&Vs[(td + dd) * 72 + tk]) =
            make_uint2((s0 & 0xffffu) | (s1 << 16), (s2 & 0xffffu) | (s3 << 16));
      }
    }
    __syncthreads();

#pragma unroll
    for (int mt = 0; mt < 2; mt++) {
      f32x4 sacc[4] = {};
#pragma unroll
      for (int c = 0; c < 4; c++) {
#pragma unroll
        for (int s = 0; s < 2; s++) {
          frag16 bh = *reinterpret_cast<const frag16*>(&Ks[(c * 16 + ln) * 72 + s * 32 + qd * 8]);
          sacc[c] = __builtin_amdgcn_mfma_f32_16x16x32_bf16(qa_h[mt][s], bh, sacc[c], 0, 0, 0);
        }
      }
#pragma unroll
      for (int c = 0; c < 4; c++) {
#pragma unroll
        for (int r = 0; r < 4; r++) {
          int tg = t0 + c * 16 + ln;
          float p = (tg < TOPK) ? __expf(sacc[c][r]) : 0.f;
          lsum[mt][r] += p;
          Ps[(wave * 32 + mt * 16 + qd * 4 + r) * 72 + c * 16 + ln] = (short)f2bf(p);
        }
      }
    }

#pragma unroll
    for (int mt = 0; mt < 2; mt++)
#pragma unroll
      for (int s = 0; s < 2; s++) {
        frag16 pa = *reinterpret_cast<const frag16*>(
            &Ps[(wave * 32 + mt * 16 + ln) * 72 + s * 32 + qd * 8]);
#pragma unroll
        for (int dt = 0; dt < 4; dt++) {
          frag16 vb = *reinterpret_cast<const frag16*>(&Vs[(dt * 16 + ln) * 72 + s * 32 + qd * 8]);
          acc_o[mt][dt] = __builtin_amdgcn_mfma_f32_16x16x32_bf16(pa, vb, acc_o[mt][dt], 0, 0, 0);
        }
      }
    __syncthreads();
  }

#pragma unroll
  for (int mt = 0; mt < 2; mt++)
#pragma unroll
    for (int r = 0; r < 4; r++) {
      float l = lsum[mt][r];
      l += __shfl_xor(l, 1);
      l += __shfl_xor(l, 2);
      l += __shfl_xor(l, 4);
      l += __shfl_xor(l, 8);
      lsum[mt][r] = 1.f / l;
    }

#pragma unroll
  for (int mt = 0; mt < 2; mt++)
#pragma unroll
    for (int dt = 0; dt < 4; dt++)
#pragma unroll
      for (int r = 0; r < 4; r++)
        Ps[(wave * 32 + mt * 16 + qd * 4 + r) * 72 + dt * 16 + ln] =
            (short)f2bf(acc_o[mt][dt][r] * lsum[mt][r]);
  __syncthreads();
#pragma unroll
  for (int p = 0; p < 4; p++) {
    int u = tid + p * 256;
    int row = u >> 3, c = (u & 7) * 8;
    *reinterpret_cast<uint4*>(xahi + (size_t)(tokbase + row) * C_DIM + h * DH + c) =
        *reinterpret_cast<const uint4*>(&Ps[row * 72 + c]);
  }
}

// ---------------------------------------------------------------------------
extern "C" void kernel_launch(void* const* d_in, const int* in_sizes, int n_in,
                              void* d_out, int out_size, void* d_ws, size_t ws_size,
                              hipStream_t stream) {
  const float* x = (const float*)d_in[0];
  const float* w_qkv = (const float*)d_in[1];
  const float* b_qkv = (const float*)d_in[2];
  const float* w_proj = (const float*)d_in[3];
  const float* b_proj = (const float*)d_in[4];
  const int* keyframes = (const int*)d_in[5];
  const int* clusters = (const int*)d_in[6];
  float* out = (float*)d_out;
  float* ws = (float*)d_ws;

  unsigned short* qhi = (unsigned short*)(ws + WS_QHI);
  unsigned short* khi = (unsigned short*)(ws + WS_KHI);
  unsigned short* vhi = (unsigned short*)(ws + WS_VHI);
  unsigned short* xahi = (unsigned short*)(ws + WS_XAHI);
  float* xbarp = ws + WS_XBARP;
  float* qbar = ws + WS_QBAR;
  float* g = ws + WS_G;
  float* agg = ws + WS_AGG;
  int* topkp = (int*)(ws + WS_TOPK);
  int* bar = (int*)(ws + WS_BAR);

  // 0. zero grid-barrier counters (graph-capturable async memset)
  hipMemsetAsync(bar, 0, 8 * sizeof(int), stream);
  // 1. QKV GEMM (reads x, w_qkv fp32 directly; cvt in staging)
  gemm_qkv<<<768, 256, 0, stream>>>(x, w_qkv, b_qkv, qhi, khi, vhi);
  // 2. fused fp32 ranking chain -> topk (load-poll grid barriers)
  rank_fused<<<256, 256, 0, stream>>>(x, w_qkv, b_qkv, keyframes, xbarp,
                                      qbar, g, agg, topkp, bar);
  // 3. fused MFMA attention
  flash_mfma<<<dim3(MPC / 128, KCLUST, NH), 256, 0, stream>>>(
      qhi, khi, vhi, topkp, clusters, xahi);
  // 4. projection GEMM (reads w_proj fp32 directly)
  gemm_proj<<<512, 256, 0, stream>>>(xahi, w_proj, b_proj, out);
}

// Round 14
// 265.593 us; speedup vs baseline: 1.0495x; 1.0453x over previous
//
#include <hip/hip_runtime.h>
#include <hip/hip_bf16.h>

#define N_TOK 8192
#define C_DIM 512
#define NH 8
#define DH 64
#define KCLUST 4
#define TPF 512
#define TOPK 204
#define MPC 2048

// ---- workspace layout (float offsets) ----
#define WS_QHI    0            // q hi (pre-scaled 0.125): 4194304 shorts
#define WS_KHI    2097152
#define WS_VHI    4194304
#define WS_XAHI   6291456      // xattn hi
#define WS_XBARP  8388608      // 4*16*512
#define WS_M      8421376      // 512*512 fp32 (Wq^T Wk)
#define WS_GB     8683520      // 512
#define WS_G      8684032      // 4*512
#define WS_AGG    8686080      // 4*8192
#define WS_TOPK   8718848      // ints 4*204

using frag16 = __attribute__((ext_vector_type(8))) short;
using f32x4  = __attribute__((ext_vector_type(4))) float;

__device__ __forceinline__ unsigned short f2bf(float x) {
  unsigned u = __float_as_uint(x);
  return (unsigned short)((u + 0x7fffu + ((u >> 16) & 1u)) >> 16);
}
__device__ __forceinline__ float bf2f(unsigned short h) {
  return __uint_as_float(((unsigned)h) << 16);
}
// packed RNE cvt of 2 floats -> 2 bf16 bit-patterns (v_cvt_pk_bf16_f32)
__device__ __forceinline__ unsigned pkbf(float a, float b) {
  __hip_bfloat162 t = __float22bfloat162_rn(make_float2(a, b));
  return *reinterpret_cast<unsigned*>(&t);
}

// ---------------------------------------------------------------------------
// mega1: three independent roles in one launch.
//   [0,768)    QKV GEMM (128x128 tile, staging-cvt, 1-barrier K-loop, swizzle)
//   [768,832)  xbar partials (kk,s): sum 32 keyframe tokens over 512 ch
//   [832,896)  M = Wq^T Wk (64x64 fp32 tiles) + gb = b_q^T Wk
// ---------------------------------------------------------------------------
#define APAN 1032
#define BUFS 8256  // 4*APAN (A) + 4*APAN (B)
__global__ __launch_bounds__(256) void mega1(
    const float* __restrict__ x, const float* __restrict__ w_qkv,
    const float* __restrict__ b_qkv, const int* __restrict__ keyframes,
    unsigned short* __restrict__ qhi, unsigned short* __restrict__ khi,
    unsigned short* __restrict__ vhi, float* __restrict__ xbarp,
    float* __restrict__ M, float* __restrict__ gb) {
  __shared__ short pool[17408];
  const int tid = threadIdx.x;
  const int bid = blockIdx.x;

  if (bid >= 832) {  // ---- role: M = Wq^T Wk (+gb) ----
    float* As = reinterpret_cast<float*>(pool);        // [32][64]
    float* Bs = As + 2048;                             // [32][64]
    const int b = bid - 832;
    const int i0 = (b >> 3) * 64, c0 = (b & 7) * 64;
    const int tx = tid & 15, ty = tid >> 4;
    const float* wk = w_qkv + (size_t)C_DIM * C_DIM;
    float acc[4][4] = {};
    float gba[4] = {};
    for (int j0 = 0; j0 < C_DIM; j0 += 32) {
#pragma unroll
      for (int e = 0; e < 8; e++) {
        int u = tid + e * 256;
        int r = u >> 6, i = u & 63;
        As[r * 64 + i] = w_qkv[(size_t)(j0 + r) * C_DIM + i0 + i];
        Bs[r * 64 + i] = wk[(size_t)(j0 + r) * C_DIM + c0 + i];
      }
      __syncthreads();
      for (int jj = 0; jj < 32; jj++) {
        float a0 = As[jj * 64 + ty * 4], a1 = As[jj * 64 + ty * 4 + 1];
        float a2 = As[jj * 64 + ty * 4 + 2], a3 = As[jj * 64 + ty * 4 + 3];
        float b0 = Bs[jj * 64 + tx * 4], b1 = Bs[jj * 64 + tx * 4 + 1];
        float b2 = Bs[jj * 64 + tx * 4 + 2], b3 = Bs[jj * 64 + tx * 4 + 3];
        acc[0][0] += a0 * b0; acc[0][1] += a0 * b1; acc[0][2] += a0 * b2; acc[0][3] += a0 * b3;
        acc[1][0] += a1 * b0; acc[1][1] += a1 * b1; acc[1][2] += a1 * b2; acc[1][3] += a1 * b3;
        acc[2][0] += a2 * b0; acc[2][1] += a2 * b1; acc[2][2] += a2 * b2; acc[2][3] += a2 * b3;
        acc[3][0] += a3 * b0; acc[3][1] += a3 * b1; acc[3][2] += a3 * b2; acc[3][3] += a3 * b3;
        if (i0 == 0) {
          float bq = b_qkv[j0 + jj];
          gba[0] += bq * b0; gba[1] += bq * b1; gba[2] += bq * b2; gba[3] += bq * b3;
        }
      }
      __syncthreads();
    }
#pragma unroll
    for (int ii = 0; ii < 4; ii++)
#pragma unroll
      for (int cc = 0; cc < 4; cc++)
        M[(size_t)(i0 + ty * 4 + ii) * C_DIM + c0 + tx * 4 + cc] = acc[ii][cc];
    if (i0 == 0 && ty == 0)
#pragma unroll
      for (int cc = 0; cc < 4; cc++) gb[c0 + tx * 4 + cc] = gba[cc];
    return;
  }

  if (bid >= 768) {  // ---- role: xbar partials ----
    int b = bid - 768, kk = b >> 4, s = b & 15;
    int base = keyframes[kk] * TPF + s * 32;
    float a0 = 0.f, a1 = 0.f;
    for (int t = 0; t < 32; t++) {
      a0 += x[(size_t)(base + t) * C_DIM + tid];
      a1 += x[(size_t)(base + t) * C_DIM + tid + 256];
    }
    xbarp[(kk * 16 + s) * C_DIM + tid] = a0;
    xbarp[(kk * 16 + s) * C_DIM + tid + 256] = a1;
    return;
  }

  // ---- role: QKV GEMM (R13 validated body) ----
  const int grp = bid / 96;
  const int rem = bid - grp * 96;
  const int jblk = rem >> 3;
  const int m_idx = grp * 8 + (rem & 7);
  const int j0 = jblk * 128;
  const int m0 = m_idx * 128;
  const int wave = tid >> 6, lane = tid & 63;
  const int wr = wave >> 1, wc = wave & 1;
  const int qd = lane >> 4, ln = lane & 15;

  const int r0 = tid >> 2, p0 = tid & 3;
  const int r1 = r0 + 64;
  const float4* pA0 = reinterpret_cast<const float4*>(x + (size_t)(m0 + r0) * C_DIM) + p0 * 2;
  const float4* pA1 = reinterpret_cast<const float4*>(x + (size_t)(m0 + r1) * C_DIM) + p0 * 2;
  const float4* pB0 = reinterpret_cast<const float4*>(w_qkv + (size_t)(j0 + r0) * C_DIM) + p0 * 2;
  const float4* pB1 = reinterpret_cast<const float4*>(w_qkv + (size_t)(j0 + r1) * C_DIM) + p0 * 2;

  f32x4 acc[4][4] = {};

  float4 fa[4], fb[4];
  fa[0] = pA0[0]; fa[1] = pA0[1];
  fa[2] = pA1[0]; fa[3] = pA1[1];
  fb[0] = pB0[0]; fb[1] = pB0[1];
  fb[2] = pB1[0]; fb[3] = pB1[1];

  {
    *reinterpret_cast<uint4*>(&pool[p0 * APAN + r0 * 8]) =
        make_uint4(pkbf(fa[0].x, fa[0].y), pkbf(fa[0].z, fa[0].w),
                   pkbf(fa[1].x, fa[1].y), pkbf(fa[1].z, fa[1].w));
    *reinterpret_cast<uint4*>(&pool[p0 * APAN + r1 * 8]) =
        make_uint4(pkbf(fa[2].x, fa[2].y), pkbf(fa[2].z, fa[2].w),
                   pkbf(fa[3].x, fa[3].y), pkbf(fa[3].z, fa[3].w));
    *reinterpret_cast<uint4*>(&pool[4 * APAN + p0 * APAN + r0 * 8]) =
        make_uint4(pkbf(fb[0].x, fb[0].y), pkbf(fb[0].z, fb[0].w),
                   pkbf(fb[1].x, fb[1].y), pkbf(fb[1].z, fb[1].w));
    *reinterpret_cast<uint4*>(&pool[4 * APAN + p0 * APAN + r1 * 8]) =
        make_uint4(pkbf(fb[2].x, fb[2].y), pkbf(fb[2].z, fb[2].w),
                   pkbf(fb[3].x, fb[3].y), pkbf(fb[3].z, fb[3].w));
  }
  __syncthreads();

  int cur = 0;
#pragma unroll
  for (int it = 0; it < 16; it++) {
    if (it < 15) {
      int k4 = (it + 1) * 8;
      fa[0] = pA0[k4]; fa[1] = pA0[k4 + 1];
      fa[2] = pA1[k4]; fa[3] = pA1[k4 + 1];
      fb[0] = pB0[k4]; fb[1] = pB0[k4 + 1];
      fb[2] = pB1[k4]; fb[3] = pB1[k4 + 1];
    }
    const int bb = cur * BUFS;
    frag16 a_h[4], b_h[4];
#pragma unroll
    for (int i = 0; i < 4; i++) {
      int row = wr * 64 + i * 16 + ln;
      a_h[i] = *reinterpret_cast<const frag16*>(&pool[bb + qd * APAN + row * 8]);
    }
#pragma unroll
    for (int j = 0; j < 4; j++) {
      int row = wc * 64 + j * 16 + ln;
      b_h[j] = *reinterpret_cast<const frag16*>(&pool[bb + 4 * APAN + qd * APAN + row * 8]);
    }
#pragma unroll
    for (int i = 0; i < 4; i++)
#pragma unroll
      for (int j = 0; j < 4; j++)
        acc[i][j] = __builtin_amdgcn_mfma_f32_16x16x32_bf16(a_h[i], b_h[j], acc[i][j], 0, 0, 0);

    if (it < 15) {
      const int nb = (cur ^ 1) * BUFS;
      *reinterpret_cast<uint4*>(&pool[nb + p0 * APAN + r0 * 8]) =
          make_uint4(pkbf(fa[0].x, fa[0].y), pkbf(fa[0].z, fa[0].w),
                     pkbf(fa[1].x, fa[1].y), pkbf(fa[1].z, fa[1].w));
      *reinterpret_cast<uint4*>(&pool[nb + p0 * APAN + r1 * 8]) =
          make_uint4(pkbf(fa[2].x, fa[2].y), pkbf(fa[2].z, fa[2].w),
                     pkbf(fa[3].x, fa[3].y), pkbf(fa[3].z, fa[3].w));
      *reinterpret_cast<uint4*>(&pool[nb + 4 * APAN + p0 * APAN + r0 * 8]) =
          make_uint4(pkbf(fb[0].x, fb[0].y), pkbf(fb[0].z, fb[0].w),
                     pkbf(fb[1].x, fb[1].y), pkbf(fb[1].z, fb[1].w));
      *reinterpret_cast<uint4*>(&pool[nb + 4 * APAN + p0 * APAN + r1 * 8]) =
          make_uint4(pkbf(fb[2].x, fb[2].y), pkbf(fb[2].z, fb[2].w),
                     pkbf(fb[3].x, fb[3].y), pkbf(fb[3].z, fb[3].w));
    }
    __syncthreads();
    cur ^= 1;
  }

  const int sel = j0 >> 9;
  const float qscale = (sel == 0) ? 0.125f : 1.0f;
  unsigned short* dst0 = (sel == 0) ? qhi : ((sel == 1) ? khi : vhi);
  short* sh = pool;

#pragma unroll
  for (int i = 0; i < 4; i++)
#pragma unroll
    for (int j = 0; j < 4; j++) {
      int jcol = wc * 64 + j * 16 + ln;
      float bv = b_qkv[j0 + jcol];
#pragma unroll
      for (int r = 0; r < 4; r++) {
        int mrow = wr * 64 + i * 16 + qd * 4 + r;
        sh[mrow * 136 + jcol] = (short)f2bf((acc[i][j][r] + bv) * qscale);
      }
    }
  __syncthreads();
#pragma unroll
  for (int p = 0; p < 8; p++) {
    int u = tid + p * 256;
    int row = u >> 4, c = (u & 15) * 8;
    int hh = ((j0 + c) >> 6) & 7, d0 = c & 63;
    *reinterpret_cast<uint4*>(dst0 + ((size_t)hh * N_TOK + m0 + row) * DH + d0) =
        *reinterpret_cast<const uint4*>(&sh[row * 136 + c]);
  }
}

// ---------------------------------------------------------------------------
// g_k: g[kk][c] = xbar[kk] . M[:][c] + gb[c].  8 blocks x 256 (64c x 4kk).
// ---------------------------------------------------------------------------
__global__ __launch_bounds__(256) void g_k(const float* __restrict__ xbarp,
                                           const float* __restrict__ M,
                                           const float* __restrict__ gb,
                                           float* __restrict__ g) {
  __shared__ float xsb[KCLUST * C_DIM];
  const int tid = threadIdx.x, bid = blockIdx.x;
  for (int i = tid; i < KCLUST * C_DIM; i += 256) {
    int kk = i >> 9, ii = i & 511;
    float a = 0.f;
    for (int s = 0; s < 16; s++) a += xbarp[(kk * 16 + s) * C_DIM + ii];
    xsb[i] = a * (1.f / 512.f);
  }
  __syncthreads();
  const int c = (tid & 63) + bid * 64;
  const int kk = tid >> 6;
  float a = 0.f;
  const float* xv = xsb + kk * C_DIM;
  for (int i = 0; i < C_DIM; i++) a += xv[i] * M[(size_t)i * C_DIM + c];
  g[kk * C_DIM + c] = a + gb[c];
}

// ---------------------------------------------------------------------------
// agg[kk][n] = g[kk] . x[n]
// ---------------------------------------------------------------------------
__global__ __launch_bounds__(256) void agg2_kernel(const float* __restrict__ x,
                                                   const float* __restrict__ g,
                                                   float* __restrict__ agg) {
  __shared__ float gs[KCLUST][C_DIM];
  int tid = threadIdx.x;
  for (int i = tid; i < KCLUST * C_DIM; i += 256) gs[i >> 9][i & 511] = g[i];
  __syncthreads();
  int wave = tid >> 6, lane = tid & 63;
  int n = blockIdx.x * 4 + wave;
  const float4* xp = reinterpret_cast<const float4*>(x + (size_t)n * C_DIM);
  float4 xa = xp[lane], xb = xp[lane + 64];
  float a[4];
#pragma unroll
  for (int kk = 0; kk < 4; kk++) {
    const float4* gpv = reinterpret_cast<const float4*>(&gs[kk][0]);
    float4 ga = gpv[lane], gb2 = gpv[lane + 64];
    a[kk] = xa.x * ga.x + xa.y * ga.y + xa.z * ga.z + xa.w * ga.w +
            xb.x * gb2.x + xb.y * gb2.y + xb.z * gb2.z + xb.w * gb2.w;
  }
#pragma unroll
  for (int off = 32; off >= 1; off >>= 1) {
    a[0] += __shfl_xor(a[0], off);
    a[1] += __shfl_xor(a[1], off);
    a[2] += __shfl_xor(a[2], off);
    a[3] += __shfl_xor(a[3], off);
  }
  if (lane == 0) {
    agg[0 * N_TOK + n] = a[0];
    agg[1 * N_TOK + n] = a[1];
    agg[2 * N_TOK + n] = a[2];
    agg[3 * N_TOK + n] = a[3];
  }
}

// ---------------------------------------------------------------------------
// Deterministic top-204: 8-bit histogram radix (ties -> lowest index).
// ---------------------------------------------------------------------------
__global__ __launch_bounds__(256) void topk_kernel(const float* __restrict__ agg,
                                                   int* __restrict__ topk) {
  __shared__ unsigned sk[N_TOK];
  __shared__ int hist[256];
  __shared__ int scn[256];
  __shared__ int sel_bin, sel_rem;
  int kk = blockIdx.x, tid = threadIdx.x;
  const float* row = agg + (size_t)kk * N_TOK;

  for (int i = tid; i < N_TOK; i += 256) {
    unsigned u = __float_as_uint(row[i]);
    sk[i] = (u & 0x80000000u) ? ~u : (u | 0x80000000u);
  }
  __syncthreads();

  unsigned prefix = 0;
  int remaining = TOPK;
#pragma unroll
  for (int rnd = 3; rnd >= 0; rnd--) {
    int shift = rnd * 8;
    hist[tid] = 0;
    __syncthreads();
    for (int i = tid; i < N_TOK; i += 256) {
      unsigned key = sk[i];
      bool in = (rnd == 3) || ((key >> (shift + 8)) == prefix);
      if (in) atomicAdd(&hist[(key >> shift) & 255], 1);
    }
    __syncthreads();
    scn[tid] = hist[255 - tid];
    __syncthreads();
    for (int s = 1; s < 256; s <<= 1) {
      int add = (tid >= s) ? scn[tid - s] : 0;
      __syncthreads();
      scn[tid] += add;
      __syncthreads();
    }
    int b = tid;
    int cgt = (b == 255) ? 0 : scn[254 - b];
    if (cgt < remaining && remaining <= cgt + hist[b]) {
      sel_bin = b;
      sel_rem = remaining - cgt;
    }
    __syncthreads();
    prefix = (prefix << 8) | (unsigned)sel_bin;
    remaining = sel_rem;
    __syncthreads();
  }
  unsigned kth = prefix;

  int* out_row = topk + kk * TOPK;
  int base = tid * 32;

  int cA = 0;
  for (int i = 0; i < 32; i++) cA += (sk[base + i] > kth) ? 1 : 0;
  scn[tid] = cA;
  __syncthreads();
  for (int s = 1; s < 256; s <<= 1) {
    int add = (tid >= s) ? scn[tid - s] : 0;
    __syncthreads();
    scn[tid] += add;
    __syncthreads();
  }
  int exclA = scn[tid] - cA;
  int G = scn[255];
  __syncthreads();
  int p = exclA;
  for (int i = 0; i < 32; i++)
    if (sk[base + i] > kth) out_row[p++] = base + i;
  __syncthreads();

  int cB = 0;
  for (int i = 0; i < 32; i++) cB += (sk[base + i] == kth) ? 1 : 0;
  scn[tid] = cB;
  __syncthreads();
  for (int s = 1; s < 256; s <<= 1) {
    int add = (tid >= s) ? scn[tid - s] : 0;
    __syncthreads();
    scn[tid] += add;
    __syncthreads();
  }
  int exclB = scn[tid] - cB;
  int pos = G + exclB;
  for (int i = 0; i < 32; i++) {
    if (sk[base + i] == kth) {
      if (pos < TOPK) out_row[pos] = base + i;
      pos++;
    }
  }
}

// ---------------------------------------------------------------------------
// MFMA flash attention: 128 q/block, all hi-only, QK 1-pass, PV 1-pass.
// ---------------------------------------------------------------------------
__global__ __launch_bounds__(256) void flash_mfma(
    const unsigned short* __restrict__ qhi, const unsigned short* __restrict__ khi,
    const unsigned short* __restrict__ vhi, const int* __restrict__ topk,
    const int* __restrict__ clusters, unsigned short* __restrict__ xahi) {
  __shared__ short Ks[64 * 72];
  __shared__ short Vs[64 * 72];
  __shared__ short Ps[128 * 72];
  __shared__ int idx[TOPK];
  const int tid = threadIdx.x;
  const int qb = blockIdx.x, kk = blockIdx.y, h = blockIdx.z;
  const int wave = tid >> 6, lane = tid & 63;
  const int ln = lane & 15, qd = lane >> 4;

  for (int i = tid; i < TOPK; i += 256) idx[i] = topk[kk * TOPK + i];

  const int q_local0 = qb * 128;
  const int frame = clusters[kk * 4 + (q_local0 >> 9)];
  const int tokbase = frame * TPF + (q_local0 & 511);

  frag16 qa_h[2][2];
#pragma unroll
  for (int mt = 0; mt < 2; mt++) {
    const int tok_m = tokbase + wave * 32 + mt * 16 + ln;
    const unsigned short* qr_h = qhi + ((size_t)h * N_TOK + tok_m) * DH;
#pragma unroll
    for (int s = 0; s < 2; s++)
      qa_h[mt][s] = *reinterpret_cast<const frag16*>(qr_h + s * 32 + qd * 8);
  }

  f32x4 acc_o[2][4] = {};
  float lsum[2][4] = {};

  __syncthreads();

  for (int t0 = 0; t0 < TOPK; t0 += 64) {
#pragma unroll
    for (int i = 0; i < 2; i++) {
      int u = tid + i * 256;
      int r = u >> 3, oct = u & 7;
      int t = t0 + r;
      if (t > TOPK - 1) t = TOPK - 1;
      *reinterpret_cast<frag16*>(&Ks[r * 72 + oct * 8]) =
          *reinterpret_cast<const frag16*>(khi + ((size_t)h * N_TOK + idx[t]) * DH + oct * 8);
    }
    {
      int tk = (tid & 15) * 4, td = (tid >> 4) * 4;
      uint2 w2[4];
#pragma unroll
      for (int i = 0; i < 4; i++) {
        int t = t0 + tk + i;
        if (t > TOPK - 1) t = TOPK - 1;
        w2[i] = *reinterpret_cast<const uint2*>(vhi + ((size_t)h * N_TOK + idx[t]) * DH + td);
      }
#pragma unroll
      for (int dd = 0; dd < 4; dd++) {
        unsigned s0 = (dd < 2) ? (w2[0].x >> (16 * dd)) : (w2[0].y >> (16 * (dd - 2)));
        unsigned s1 = (dd < 2) ? (w2[1].x >> (16 * dd)) : (w2[1].y >> (16 * (dd - 2)));
        unsigned s2 = (dd < 2) ? (w2[2].x >> (16 * dd)) : (w2[2].y >> (16 * (dd - 2)));
        unsigned s3 = (dd < 2) ? (w2[3].x >> (16 * dd)) : (w2[3].y >> (16 * (dd - 2)));
        *reinterpret_cast<uint2*>(&Vs[(td + dd) * 72 + tk]) =
            make_uint2((s0 & 0xffffu) | (s1 << 16), (s2 & 0xffffu) | (s3 << 16));
      }
    }
    __syncthreads();

#pragma unroll
    for (int mt = 0; mt < 2; mt++) {
      f32x4 sacc[4] = {};
#pragma unroll
      for (int c = 0; c < 4; c++) {
#pragma unroll
        for (int s = 0; s < 2; s++) {
          frag16 bh = *reinterpret_cast<const frag16*>(&Ks[(c * 16 + ln) * 72 + s * 32 + qd * 8]);
          sacc[c] = __builtin_amdgcn_mfma_f32_16x16x32_bf16(qa_h[mt][s], bh, sacc[c], 0, 0, 0);
        }
      }
#pragma unroll
      for (int c = 0; c < 4; c++) {
#pragma unroll
        for (int r = 0; r < 4; r++) {
          int tg = t0 + c * 16 + ln;
          float p = (tg < TOPK) ? __expf(sacc[c][r]) : 0.f;
          lsum[mt][r] += p;
          Ps[(wave * 32 + mt * 16 + qd * 4 + r) * 72 + c * 16 + ln] = (short)f2bf(p);
        }
      }
    }

#pragma unroll
    for (int mt = 0; mt < 2; mt++)
#pragma unroll
      for (int s = 0; s < 2; s++) {
        frag16 pa = *reinterpret_cast<const frag16*>(
            &Ps[(wave * 32 + mt * 16 + ln) * 72 + s * 32 + qd * 8]);
#pragma unroll
        for (int dt = 0; dt < 4; dt++) {
          frag16 vb = *reinterpret_cast<const frag16*>(&Vs[(dt * 16 + ln) * 72 + s * 32 + qd * 8]);
          acc_o[mt][dt] = __builtin_amdgcn_mfma_f32_16x16x32_bf16(pa, vb, acc_o[mt][dt], 0, 0, 0);
        }
      }
    __syncthreads();
  }

#pragma unroll
  for (int mt = 0; mt < 2; mt++)
#pragma unroll
    for (int r = 0; r < 4; r++) {
      float l = lsum[mt][r];
      l += __shfl_xor(l, 1);
      l += __shfl_xor(l, 2);
      l += __shfl_xor(l, 4);
      l += __shfl_xor(l, 8);
      lsum[mt][r] = 1.f / l;
    }

#pragma unroll
  for (int mt = 0; mt < 2; mt++)
#pragma unroll
    for (int dt = 0; dt < 4; dt++)
#pragma unroll
      for (int r = 0; r < 4; r++)
        Ps[(wave * 32 + mt * 16 + qd * 4 + r) * 72 + dt * 16 + ln] =
            (short)f2bf(acc_o[mt][dt][r] * lsum[mt][r]);
  __syncthreads();
#pragma unroll
  for (int p = 0; p < 4; p++) {
    int u = tid + p * 256;
    int row = u >> 3, c = (u & 7) * 8;
    *reinterpret_cast<uint4*>(xahi + (size_t)(tokbase + row) * C_DIM + h * DH + c) =
        *reinterpret_cast<const uint4*>(&Ps[row * 72 + c]);
  }
}

// ---------------------------------------------------------------------------
// Projection GEMM: 64x128, reg-dbuf pipeline (w_proj fp32 cvt in staging),
// swizzle, fp32 LDS-transpose epilogue.
// ---------------------------------------------------------------------------
__global__ __launch_bounds__(256) void gemm_proj(
    const unsigned short* __restrict__ Ahi, const float* __restrict__ w_proj,
    const float* __restrict__ bias, float* __restrict__ out) {
  __shared__ short pool[12288];
  short* As = pool;
  short* Bs = pool + 4096;
  const int tid = threadIdx.x;
  const int bid = blockIdx.x;
  const int grp = bid / 32;
  const int rem = bid - grp * 32;
  const int jblk = rem >> 3;
  const int m_idx = grp * 8 + (rem & 7);
  const int j0 = jblk * 128;
  const int m0 = m_idx * 64;
  const int wave = tid >> 6, lane = tid & 63;
  const int rh = wave >> 1, ch = wave & 1;
  const int qd = lane >> 4, ln = lane & 15;

  const int arow = tid & 63, ap = tid >> 6;
  const int brow = tid & 127, bp = tid >> 7;
  const unsigned short* pA = Ahi + (size_t)(m0 + arow) * C_DIM + ap * 8;
  const float4* pB0 = reinterpret_cast<const float4*>(w_proj + (size_t)(j0 + brow) * C_DIM) + bp * 2;
  const float4* pB1 = pB0 + 4;

  f32x4 acc[2][4] = {};

  uint4 ra = *reinterpret_cast<const uint4*>(pA);
  float4 f0a = pB0[0], f0b = pB0[1];
  float4 f1a = pB1[0], f1b = pB1[1];
  *reinterpret_cast<uint4*>(&As[ap * 512 + arow * 8]) = ra;
  *reinterpret_cast<uint4*>(&Bs[bp * 1024 + brow * 8]) =
      make_uint4(pkbf(f0a.x, f0a.y), pkbf(f0a.z, f0a.w), pkbf(f0b.x, f0b.y), pkbf(f0b.z, f0b.w));
  *reinterpret_cast<uint4*>(&Bs[(bp + 2) * 1024 + brow * 8]) =
      make_uint4(pkbf(f1a.x, f1a.y), pkbf(f1a.z, f1a.w), pkbf(f1b.x, f1b.y), pkbf(f1b.z, f1b.w));
  __syncthreads();

  int cur = 0;
#pragma unroll
  for (int it = 0; it < 16; it++) {
    if (it < 15) {
      int k = (it + 1) * 32;
      int k4 = (it + 1) * 8;
      ra = *reinterpret_cast<const uint4*>(pA + k);
      f0a = pB0[k4]; f0b = pB0[k4 + 1];
      f1a = pB1[k4]; f1b = pB1[k4 + 1];
    }
    frag16 a_h[2], b_h[4];
#pragma unroll
    for (int i = 0; i < 2; i++)
      a_h[i] = *reinterpret_cast<const frag16*>(&As[cur * 2048 + qd * 512 + (rh * 32 + i * 16 + ln) * 8]);
#pragma unroll
    for (int j = 0; j < 4; j++)
      b_h[j] = *reinterpret_cast<const frag16*>(&Bs[cur * 4096 + qd * 1024 + (ch * 64 + j * 16 + ln) * 8]);
#pragma unroll
    for (int i = 0; i < 2; i++)
#pragma unroll
      for (int j = 0; j < 4; j++)
        acc[i][j] = __builtin_amdgcn_mfma_f32_16x16x32_bf16(a_h[i], b_h[j], acc[i][j], 0, 0, 0);
    if (it < 15) {
      int nxt = cur ^ 1;
      *reinterpret_cast<uint4*>(&As[nxt * 2048 + ap * 512 + arow * 8]) = ra;
      *reinterpret_cast<uint4*>(&Bs[nxt * 4096 + bp * 1024 + brow * 8]) =
          make_uint4(pkbf(f0a.x, f0a.y), pkbf(f0a.z, f0a.w), pkbf(f0b.x, f0b.y), pkbf(f0b.z, f0b.w));
      *reinterpret_cast<uint4*>(&Bs[nxt * 4096 + (bp + 2) * 1024 + brow * 8]) =
          make_uint4(pkbf(f1a.x, f1a.y), pkbf(f1a.z, f1a.w), pkbf(f1b.x, f1b.y), pkbf(f1b.z, f1b.w));
      __syncthreads();
      cur = nxt;
    }
  }

  float* sh32 = reinterpret_cast<float*>(pool);  // 64 x 68
#pragma unroll
  for (int chp = 0; chp < 2; chp++) {
    __syncthreads();
    if (ch == chp) {
#pragma unroll
      for (int i = 0; i < 2; i++)
#pragma unroll
        for (int j = 0; j < 4; j++) {
          int jcol = j * 16 + ln;
          float bv = bias[j0 + chp * 64 + jcol];
#pragma unroll
          for (int r = 0; r < 4; r++)
            sh32[(rh * 32 + i * 16 + qd * 4 + r) * 68 + jcol] = acc[i][j][r] + bv;
        }
    }
    __syncthreads();
#pragma unroll
    for (int p = 0; p < 4; p++) {
      int u = tid + p * 256;
      int row = u >> 4, c4 = (u & 15) * 4;
      *reinterpret_cast<float4*>(out + (size_t)(m0 + row) * C_DIM + j0 + chp * 64 + c4) =
          *reinterpret_cast<const float4*>(&sh32[row * 68 + c4]);
    }
  }
}

// ---------------------------------------------------------------------------
extern "C" void kernel_launch(void* const* d_in, const int* in_sizes, int n_in,
                              void* d_out, int out_size, void* d_ws, size_t ws_size,
                              hipStream_t stream) {
  const float* x = (const float*)d_in[0];
  const float* w_qkv = (const float*)d_in[1];
  const float* b_qkv = (const float*)d_in[2];
  const float* w_proj = (const float*)d_in[3];
  const float* b_proj = (const float*)d_in[4];
  const int* keyframes = (const int*)d_in[5];
  const int* clusters = (const int*)d_in[6];
  float* out = (float*)d_out;
  float* ws = (float*)d_ws;

  unsigned short* qhi = (unsigned short*)(ws + WS_QHI);
  unsigned short* khi = (unsigned short*)(ws + WS_KHI);
  unsigned short* vhi = (unsigned short*)(ws + WS_VHI);
  unsigned short* xahi = (unsigned short*)(ws + WS_XAHI);
  float* xbarp = ws + WS_XBARP;
  float* M = ws + WS_M;
  float* gb = ws + WS_GB;
  float* g = ws + WS_G;
  float* agg = ws + WS_AGG;
  int* topkp = (int*)(ws + WS_TOPK);

  // 1. QKV GEMM || xbar partials || M = Wq^T Wk (+gb)
  mega1<<<896, 256, 0, stream>>>(x, w_qkv, b_qkv, keyframes, qhi, khi, vhi,
                                 xbarp, M, gb);
  // 2. g = xbar . M + gb  (collapses qbar+g chain)
  g_k<<<8, 256, 0, stream>>>(xbarp, M, gb, g);
  // 3. agg[kk][n] = g[kk] . x[n]
  agg2_kernel<<<2048, 256, 0, stream>>>(x, g, agg);
  // 4. top-204 per cluster
  topk_kernel<<<4, 256, 0, stream>>>(agg, topkp);
  // 5. fused MFMA attention
  flash_mfma<<<dim3(MPC / 128, KCLUST, NH), 256, 0, stream>>>(
      qhi, khi, vhi, topkp, clusters, xahi);
  // 6. projection GEMM
  gemm_proj<<<512, 256, 0, stream>>>(xahi, w_proj, b_proj, out);
}

// Round 15
// 225.455 us; speedup vs baseline: 1.2363x; 1.1780x over previous
//
#include <hip/hip_runtime.h>
#include <hip/hip_bf16.h>

#define N_TOK 8192
#define C_DIM 512
#define NH 8
#define DH 64
#define KCLUST 4
#define TPF 512
#define TOPK 204
#define MPC 2048

// ---- workspace layout (float offsets) ----
#define WS_QHI    0            // q hi (pre-scaled 0.125): 4194304 shorts
#define WS_KHI    2097152
#define WS_VHI    4194304
#define WS_XAHI   6291456      // xattn hi
#define WS_XBARP  8388608      // 4*16*512
#define WS_QBAR   8421376      // 32*64
#define WS_G      8423424      // 4*512
#define WS_AGG    8425472      // 4*8192
#define WS_TOPK   8458240      // ints 4*204

using frag16 = __attribute__((ext_vector_type(8))) short;
using f32x4  = __attribute__((ext_vector_type(4))) float;

__device__ __forceinline__ unsigned short f2bf(float x) {
  unsigned u = __float_as_uint(x);
  return (unsigned short)((u + 0x7fffu + ((u >> 16) & 1u)) >> 16);
}
__device__ __forceinline__ float bf2f(unsigned short h) {
  return __uint_as_float(((unsigned)h) << 16);
}
// packed RNE cvt of 2 floats -> 2 bf16 bit-patterns (v_cvt_pk_bf16_f32)
__device__ __forceinline__ unsigned pkbf(float a, float b) {
  __hip_bfloat162 t = __float22bfloat162_rn(make_float2(a, b));
  return *reinterpret_cast<unsigned*>(&t);
}

// ---------------------------------------------------------------------------
// xbarp: keyframe partial sums only (weight cvts moved into GEMM staging).
// 64 blocks.
// ---------------------------------------------------------------------------
__global__ __launch_bounds__(256) void xbar_part(const float* __restrict__ x,
                                                 const int* __restrict__ keyframes,
                                                 float* __restrict__ xbarp) {
  const int b = blockIdx.x, tid = threadIdx.x;
  int kk = b >> 4, s = b & 15;
  int base = keyframes[kk] * TPF + s * 32;
  float a0 = 0.f, a1 = 0.f;
  for (int t = 0; t < 32; t++) {
    a0 += x[(size_t)(base + t) * C_DIM + tid];
    a1 += x[(size_t)(base + t) * C_DIM + tid + 256];
  }
  xbarp[(kk * 16 + s) * C_DIM + tid] = a0;
  xbarp[(kk * 16 + s) * C_DIM + tid + 256] = a1;
}

// ---------------------------------------------------------------------------
// QKV GEMM (R13-validated): 128x128, 1-pass bf16, A=x fp32 / B=w_qkv fp32
// cvt in staging, reg-staged LDS dbuf, ONE barrier/K-iter, bank-skewed
// panels (1032), XCD swizzle, transpose epilogue.
// ---------------------------------------------------------------------------
#define APAN 1032
#define BUFS 8256
__global__ __launch_bounds__(256) void gemm_qkv(
    const float* __restrict__ x, const float* __restrict__ w_qkv,
    const float* __restrict__ bias,
    unsigned short* __restrict__ qhi, unsigned short* __restrict__ khi,
    unsigned short* __restrict__ vhi) {
  __shared__ short pool[17408];
  const int tid = threadIdx.x;
  const int bid = blockIdx.x;
  const int grp = bid / 96;
  const int rem = bid - grp * 96;
  const int jblk = rem >> 3;
  const int m_idx = grp * 8 + (rem & 7);
  const int j0 = jblk * 128;
  const int m0 = m_idx * 128;
  const int wave = tid >> 6, lane = tid & 63;
  const int wr = wave >> 1, wc = wave & 1;
  const int qd = lane >> 4, ln = lane & 15;

  const int r0 = tid >> 2, p0 = tid & 3;
  const int r1 = r0 + 64;
  const float4* pA0 = reinterpret_cast<const float4*>(x + (size_t)(m0 + r0) * C_DIM) + p0 * 2;
  const float4* pA1 = reinterpret_cast<const float4*>(x + (size_t)(m0 + r1) * C_DIM) + p0 * 2;
  const float4* pB0 = reinterpret_cast<const float4*>(w_qkv + (size_t)(j0 + r0) * C_DIM) + p0 * 2;
  const float4* pB1 = reinterpret_cast<const float4*>(w_qkv + (size_t)(j0 + r1) * C_DIM) + p0 * 2;

  f32x4 acc[4][4] = {};

  float4 fa[4], fb[4];
  fa[0] = pA0[0]; fa[1] = pA0[1];
  fa[2] = pA1[0]; fa[3] = pA1[1];
  fb[0] = pB0[0]; fb[1] = pB0[1];
  fb[2] = pB1[0]; fb[3] = pB1[1];

  {
    *reinterpret_cast<uint4*>(&pool[p0 * APAN + r0 * 8]) =
        make_uint4(pkbf(fa[0].x, fa[0].y), pkbf(fa[0].z, fa[0].w),
                   pkbf(fa[1].x, fa[1].y), pkbf(fa[1].z, fa[1].w));
    *reinterpret_cast<uint4*>(&pool[p0 * APAN + r1 * 8]) =
        make_uint4(pkbf(fa[2].x, fa[2].y), pkbf(fa[2].z, fa[2].w),
                   pkbf(fa[3].x, fa[3].y), pkbf(fa[3].z, fa[3].w));
    *reinterpret_cast<uint4*>(&pool[4 * APAN + p0 * APAN + r0 * 8]) =
        make_uint4(pkbf(fb[0].x, fb[0].y), pkbf(fb[0].z, fb[0].w),
                   pkbf(fb[1].x, fb[1].y), pkbf(fb[1].z, fb[1].w));
    *reinterpret_cast<uint4*>(&pool[4 * APAN + p0 * APAN + r1 * 8]) =
        make_uint4(pkbf(fb[2].x, fb[2].y), pkbf(fb[2].z, fb[2].w),
                   pkbf(fb[3].x, fb[3].y), pkbf(fb[3].z, fb[3].w));
  }
  __syncthreads();

  int cur = 0;
#pragma unroll
  for (int it = 0; it < 16; it++) {
    if (it < 15) {
      int k4 = (it + 1) * 8;
      fa[0] = pA0[k4]; fa[1] = pA0[k4 + 1];
      fa[2] = pA1[k4]; fa[3] = pA1[k4 + 1];
      fb[0] = pB0[k4]; fb[1] = pB0[k4 + 1];
      fb[2] = pB1[k4]; fb[3] = pB1[k4 + 1];
    }
    const int bb = cur * BUFS;
    frag16 a_h[4], b_h[4];
#pragma unroll
    for (int i = 0; i < 4; i++) {
      int row = wr * 64 + i * 16 + ln;
      a_h[i] = *reinterpret_cast<const frag16*>(&pool[bb + qd * APAN + row * 8]);
    }
#pragma unroll
    for (int j = 0; j < 4; j++) {
      int row = wc * 64 + j * 16 + ln;
      b_h[j] = *reinterpret_cast<const frag16*>(&pool[bb + 4 * APAN + qd * APAN + row * 8]);
    }
#pragma unroll
    for (int i = 0; i < 4; i++)
#pragma unroll
      for (int j = 0; j < 4; j++)
        acc[i][j] = __builtin_amdgcn_mfma_f32_16x16x32_bf16(a_h[i], b_h[j], acc[i][j], 0, 0, 0);

    if (it < 15) {
      const int nb = (cur ^ 1) * BUFS;
      *reinterpret_cast<uint4*>(&pool[nb + p0 * APAN + r0 * 8]) =
          make_uint4(pkbf(fa[0].x, fa[0].y), pkbf(fa[0].z, fa[0].w),
                     pkbf(fa[1].x, fa[1].y), pkbf(fa[1].z, fa[1].w));
      *reinterpret_cast<uint4*>(&pool[nb + p0 * APAN + r1 * 8]) =
          make_uint4(pkbf(fa[2].x, fa[2].y), pkbf(fa[2].z, fa[2].w),
                     pkbf(fa[3].x, fa[3].y), pkbf(fa[3].z, fa[3].w));
      *reinterpret_cast<uint4*>(&pool[nb + 4 * APAN + p0 * APAN + r0 * 8]) =
          make_uint4(pkbf(fb[0].x, fb[0].y), pkbf(fb[0].z, fb[0].w),
                     pkbf(fb[1].x, fb[1].y), pkbf(fb[1].z, fb[1].w));
      *reinterpret_cast<uint4*>(&pool[nb + 4 * APAN + p0 * APAN + r1 * 8]) =
          make_uint4(pkbf(fb[2].x, fb[2].y), pkbf(fb[2].z, fb[2].w),
                     pkbf(fb[3].x, fb[3].y), pkbf(fb[3].z, fb[3].w));
    }
    __syncthreads();
    cur ^= 1;
  }

  const int sel = j0 >> 9;
  const float qscale = (sel == 0) ? 0.125f : 1.0f;
  unsigned short* dst0 = (sel == 0) ? qhi : ((sel == 1) ? khi : vhi);
  short* sh = pool;

#pragma unroll
  for (int i = 0; i < 4; i++)
#pragma unroll
    for (int j = 0; j < 4; j++) {
      int jcol = wc * 64 + j * 16 + ln;
      float bv = bias[j0 + jcol];
#pragma unroll
      for (int r = 0; r < 4; r++) {
        int mrow = wr * 64 + i * 16 + qd * 4 + r;
        sh[mrow * 136 + jcol] = (short)f2bf((acc[i][j][r] + bv) * qscale);
      }
    }
  __syncthreads();
#pragma unroll
  for (int p = 0; p < 8; p++) {
    int u = tid + p * 256;
    int row = u >> 4, c = (u & 15) * 8;
    int hh = ((j0 + c) >> 6) & 7, d0 = c & 63;
    *reinterpret_cast<uint4*>(dst0 + ((size_t)hh * N_TOK + m0 + row) * DH + d0) =
        *reinterpret_cast<const uint4*>(&sh[row * 136 + c]);
  }
}

// ---------------------------------------------------------------------------
// qbar[h][kk][d] = W_q . mean(x over keyframe kk) + b_q  (R11-validated)
// ---------------------------------------------------------------------------
__global__ __launch_bounds__(256) void qbar_k(const float* __restrict__ w_qkv,
                                              const float* __restrict__ b_qkv,
                                              const float* __restrict__ xbarp,
                                              float* __restrict__ qbar) {
  __shared__ float xs[C_DIM];
  __shared__ float red[256];
  int blk = blockIdx.x, h = blk >> 2, kk = blk & 3, tid = threadIdx.x;
  for (int i = tid; i < C_DIM; i += 256) {
    float a = 0.f;
    for (int s = 0; s < 16; s++) a += xbarp[(kk * 16 + s) * C_DIM + i];
    xs[i] = a * (1.f / 512.f);
  }
  __syncthreads();
  int d = tid & 63, pp = tid >> 6;
  const float* wrow = w_qkv + (size_t)(h * 64 + d) * C_DIM + pp * 128;
  float a = 0.f;
  for (int c = 0; c < 128; c++) a += wrow[c] * xs[pp * 128 + c];
  red[tid] = a;
  __syncthreads();
  if (pp == 0)
    qbar[(h * 4 + kk) * 64 + d] = red[d] + red[64 + d] + red[128 + d] + red[192 + d] +
                                  b_qkv[h * 64 + d];
}

// ---------------------------------------------------------------------------
// g[kk][c] = sum_j qbar[kk][j] W_k[j][c]  (R11-validated)
// ---------------------------------------------------------------------------
__global__ __launch_bounds__(256) void g_full(const float* __restrict__ w_qkv,
                                              const float* __restrict__ qbar,
                                              float* __restrict__ g) {
  __shared__ float qs[C_DIM];
  __shared__ float red[256];
  int kk = blockIdx.x >> 3, cs = blockIdx.x & 7, tid = threadIdx.x;
  for (int i = tid; i < C_DIM; i += 256)
    qs[i] = qbar[((i >> 6) * 4 + kk) * 64 + (i & 63)];
  __syncthreads();
  int jg = tid >> 6, c = tid & 63;
  float a = 0.f;
  const float* wk = w_qkv + (size_t)C_DIM * C_DIM + cs * 64 + c;
  for (int j = jg * 128; j < jg * 128 + 128; j++)
    a += qs[j] * wk[(size_t)j * C_DIM];
  red[tid] = a;
  __syncthreads();
  if (jg == 0)
    g[kk * C_DIM + cs * 64 + c] = red[c] + red[64 + c] + red[128 + c] + red[192 + c];
}

// ---------------------------------------------------------------------------
// agg[kk][n] = g[kk] . x[n]  (R11-validated)
// ---------------------------------------------------------------------------
__global__ __launch_bounds__(256) void agg2_kernel(const float* __restrict__ x,
                                                   const float* __restrict__ g,
                                                   float* __restrict__ agg) {
  __shared__ float gs[KCLUST][C_DIM];
  int tid = threadIdx.x;
  for (int i = tid; i < KCLUST * C_DIM; i += 256) gs[i >> 9][i & 511] = g[i];
  __syncthreads();
  int wave = tid >> 6, lane = tid & 63;
  int n = blockIdx.x * 4 + wave;
  const float4* xp = reinterpret_cast<const float4*>(x + (size_t)n * C_DIM);
  float4 xa = xp[lane], xb = xp[lane + 64];
  float a[4];
#pragma unroll
  for (int kk = 0; kk < 4; kk++) {
    const float4* gpv = reinterpret_cast<const float4*>(&gs[kk][0]);
    float4 ga = gpv[lane], gb2 = gpv[lane + 64];
    a[kk] = xa.x * ga.x + xa.y * ga.y + xa.z * ga.z + xa.w * ga.w +
            xb.x * gb2.x + xb.y * gb2.y + xb.z * gb2.z + xb.w * gb2.w;
  }
#pragma unroll
  for (int off = 32; off >= 1; off >>= 1) {
    a[0] += __shfl_xor(a[0], off);
    a[1] += __shfl_xor(a[1], off);
    a[2] += __shfl_xor(a[2], off);
    a[3] += __shfl_xor(a[3], off);
  }
  if (lane == 0) {
    agg[0 * N_TOK + n] = a[0];
    agg[1 * N_TOK + n] = a[1];
    agg[2 * N_TOK + n] = a[2];
    agg[3 * N_TOK + n] = a[3];
  }
}

// ---------------------------------------------------------------------------
// Deterministic top-204: 8-bit histogram radix (ties -> lowest index).
// ---------------------------------------------------------------------------
__global__ __launch_bounds__(256) void topk_kernel(const float* __restrict__ agg,
                                                   int* __restrict__ topk) {
  __shared__ unsigned sk[N_TOK];
  __shared__ int hist[256];
  __shared__ int scn[256];
  __shared__ int sel_bin, sel_rem;
  int kk = blockIdx.x, tid = threadIdx.x;
  const float* row = agg + (size_t)kk * N_TOK;

  for (int i = tid; i < N_TOK; i += 256) {
    unsigned u = __float_as_uint(row[i]);
    sk[i] = (u & 0x80000000u) ? ~u : (u | 0x80000000u);
  }
  __syncthreads();

  unsigned prefix = 0;
  int remaining = TOPK;
#pragma unroll
  for (int rnd = 3; rnd >= 0; rnd--) {
    int shift = rnd * 8;
    hist[tid] = 0;
    __syncthreads();
    for (int i = tid; i < N_TOK; i += 256) {
      unsigned key = sk[i];
      bool in = (rnd == 3) || ((key >> (shift + 8)) == prefix);
      if (in) atomicAdd(&hist[(key >> shift) & 255], 1);
    }
    __syncthreads();
    scn[tid] = hist[255 - tid];
    __syncthreads();
    for (int s = 1; s < 256; s <<= 1) {
      int add = (tid >= s) ? scn[tid - s] : 0;
      __syncthreads();
      scn[tid] += add;
      __syncthreads();
    }
    int b = tid;
    int cgt = (b == 255) ? 0 : scn[254 - b];
    if (cgt < remaining && remaining <= cgt + hist[b]) {
      sel_bin = b;
      sel_rem = remaining - cgt;
    }
    __syncthreads();
    prefix = (prefix << 8) | (unsigned)sel_bin;
    remaining = sel_rem;
    __syncthreads();
  }
  unsigned kth = prefix;

  int* out_row = topk + kk * TOPK;
  int base = tid * 32;

  int cA = 0;
  for (int i = 0; i < 32; i++) cA += (sk[base + i] > kth) ? 1 : 0;
  scn[tid] = cA;
  __syncthreads();
  for (int s = 1; s < 256; s <<= 1) {
    int add = (tid >= s) ? scn[tid - s] : 0;
    __syncthreads();
    scn[tid] += add;
    __syncthreads();
  }
  int exclA = scn[tid] - cA;
  int G = scn[255];
  __syncthreads();
  int p = exclA;
  for (int i = 0; i < 32; i++)
    if (sk[base + i] > kth) out_row[p++] = base + i;
  __syncthreads();

  int cB = 0;
  for (int i = 0; i < 32; i++) cB += (sk[base + i] == kth) ? 1 : 0;
  scn[tid] = cB;
  __syncthreads();
  for (int s = 1; s < 256; s <<= 1) {
    int add = (tid >= s) ? scn[tid - s] : 0;
    __syncthreads();
    scn[tid] += add;
    __syncthreads();
  }
  int exclB = scn[tid] - cB;
  int pos = G + exclB;
  for (int i = 0; i < 32; i++) {
    if (sk[base + i] == kth) {
      if (pos < TOPK) out_row[pos] = base + i;
      pos++;
    }
  }
}

// ---------------------------------------------------------------------------
// MFMA flash attention (R11-validated): 128 q/block, hi-only, 1-pass QK/PV.
// ---------------------------------------------------------------------------
__global__ __launch_bounds__(256) void flash_mfma(
    const unsigned short* __restrict__ qhi, const unsigned short* __restrict__ khi,
    const unsigned short* __restrict__ vhi, const int* __restrict__ topk,
    const int* __restrict__ clusters, unsigned short* __restrict__ xahi) {
  __shared__ short Ks[64 * 72];
  __shared__ short Vs[64 * 72];
  __shared__ short Ps[128 * 72];
  __shared__ int idx[TOPK];
  const int tid = threadIdx.x;
  const int qb = blockIdx.x, kk = blockIdx.y, h = blockIdx.z;
  const int wave = tid >> 6, lane = tid & 63;
  const int ln = lane & 15, qd = lane >> 4;

  for (int i = tid; i < TOPK; i += 256) idx[i] = topk[kk * TOPK + i];

  const int q_local0 = qb * 128;
  const int frame = clusters[kk * 4 + (q_local0 >> 9)];
  const int tokbase = frame * TPF + (q_local0 & 511);

  frag16 qa_h[2][2];
#pragma unroll
  for (int mt = 0; mt < 2; mt++) {
    const int tok_m = tokbase + wave * 32 + mt * 16 + ln;
    const unsigned short* qr_h = qhi + ((size_t)h * N_TOK + tok_m) * DH;
#pragma unroll
    for (int s = 0; s < 2; s++)
      qa_h[mt][s] = *reinterpret_cast<const frag16*>(qr_h + s * 32 + qd * 8);
  }

  f32x4 acc_o[2][4] = {};
  float lsum[2][4] = {};

  __syncthreads();

  for (int t0 = 0; t0 < TOPK; t0 += 64) {
#pragma unroll
    for (int i = 0; i < 2; i++) {
      int u = tid + i * 256;
      int r = u >> 3, oct = u & 7;
      int t = t0 + r;
      if (t > TOPK - 1) t = TOPK - 1;
      *reinterpret_cast<frag16*>(&Ks[r * 72 + oct * 8]) =
          *reinterpret_cast<const frag16*>(khi + ((size_t)h * N_TOK + idx[t]) * DH + oct * 8);
    }
    {
      int tk = (tid & 15) * 4, td = (tid >> 4) * 4;
      uint2 w2[4];
#pragma unroll
      for (int i = 0; i < 4; i++) {
        int t = t0 + tk + i;
        if (t > TOPK - 1) t = TOPK - 1;
        w2[i] = *reinterpret_cast<const uint2*>(vhi + ((size_t)h * N_TOK + idx[t]) * DH + td);
      }
#pragma unroll
      for (int dd = 0; dd < 4; dd++) {
        unsigned s0 = (dd < 2) ? (w2[0].x >> (16 * dd)) : (w2[0].y >> (16 * (dd - 2)));
        unsigned s1 = (dd < 2) ? (w2[1].x >> (16 * dd)) : (w2[1].y >> (16 * (dd - 2)));
        unsigned s2 = (dd < 2) ? (w2[2].x >> (16 * dd)) : (w2[2].y >> (16 * (dd - 2)));
        unsigned s3 = (dd < 2) ? (w2[3].x >> (16 * dd)) : (w2[3].y >> (16 * (dd - 2)));
        *reinterpret_cast<uint2*>(&Vs[(td + dd) * 72 + tk]) =
            make_uint2((s0 & 0xffffu) | (s1 << 16), (s2 & 0xffffu) | (s3 << 16));
      }
    }
    __syncthreads();

#pragma unroll
    for (int mt = 0; mt < 2; mt++) {
      f32x4 sacc[4] = {};
#pragma unroll
      for (int c = 0; c < 4; c++) {
#pragma unroll
        for (int s = 0; s < 2; s++) {
          frag16 bh = *reinterpret_cast<const frag16*>(&Ks[(c * 16 + ln) * 72 + s * 32 + qd * 8]);
          sacc[c] = __builtin_amdgcn_mfma_f32_16x16x32_bf16(qa_h[mt][s], bh, sacc[c], 0, 0, 0);
        }
      }
#pragma unroll
      for (int c = 0; c < 4; c++) {
#pragma unroll
        for (int r = 0; r < 4; r++) {
          int tg = t0 + c * 16 + ln;
          float p = (tg < TOPK) ? __expf(sacc[c][r]) : 0.f;
          lsum[mt][r] += p;
          Ps[(wave * 32 + mt * 16 + qd * 4 + r) * 72 + c * 16 + ln] = (short)f2bf(p);
        }
      }
    }

#pragma unroll
    for (int mt = 0; mt < 2; mt++)
#pragma unroll
      for (int s = 0; s < 2; s++) {
        frag16 pa = *reinterpret_cast<const frag16*>(
            &Ps[(wave * 32 + mt * 16 + ln) * 72 + s * 32 + qd * 8]);
#pragma unroll
        for (int dt = 0; dt < 4; dt++) {
          frag16 vb = *reinterpret_cast<const frag16*>(&Vs[(dt * 16 + ln) * 72 + s * 32 + qd * 8]);
          acc_o[mt][dt] = __builtin_amdgcn_mfma_f32_16x16x32_bf16(pa, vb, acc_o[mt][dt], 0, 0, 0);
        }
      }
    __syncthreads();
  }

#pragma unroll
  for (int mt = 0; mt < 2; mt++)
#pragma unroll
    for (int r = 0; r < 4; r++) {
      float l = lsum[mt][r];
      l += __shfl_xor(l, 1);
      l += __shfl_xor(l, 2);
      l += __shfl_xor(l, 4);
      l += __shfl_xor(l, 8);
      lsum[mt][r] = 1.f / l;
    }

#pragma unroll
  for (int mt = 0; mt < 2; mt++)
#pragma unroll
    for (int dt = 0; dt < 4; dt++)
#pragma unroll
      for (int r = 0; r < 4; r++)
        Ps[(wave * 32 + mt * 16 + qd * 4 + r) * 72 + dt * 16 + ln] =
            (short)f2bf(acc_o[mt][dt][r] * lsum[mt][r]);
  __syncthreads();
#pragma unroll
  for (int p = 0; p < 4; p++) {
    int u = tid + p * 256;
    int row = u >> 3, c = (u & 7) * 8;
    *reinterpret_cast<uint4*>(xahi + (size_t)(tokbase + row) * C_DIM + h * DH + c) =
        *reinterpret_cast<const uint4*>(&Ps[row * 72 + c]);
  }
}

// ---------------------------------------------------------------------------
// Projection GEMM (R13-validated): 64x128, reg-dbuf pipeline, w_proj fp32
// cvt in staging, swizzle, fp32 LDS-transpose epilogue.
// ---------------------------------------------------------------------------
__global__ __launch_bounds__(256) void gemm_proj(
    const unsigned short* __restrict__ Ahi, const float* __restrict__ w_proj,
    const float* __restrict__ bias, float* __restrict__ out) {
  __shared__ short pool[12288];
  short* As = pool;
  short* Bs = pool + 4096;
  const int tid = threadIdx.x;
  const int bid = blockIdx.x;
  const int grp = bid / 32;
  const int rem = bid - grp * 32;
  const int jblk = rem >> 3;
  const int m_idx = grp * 8 + (rem & 7);
  const int j0 = jblk * 128;
  const int m0 = m_idx * 64;
  const int wave = tid >> 6, lane = tid & 63;
  const int rh = wave >> 1, ch = wave & 1;
  const int qd = lane >> 4, ln = lane & 15;

  const int arow = tid & 63, ap = tid >> 6;
  const int brow = tid & 127, bp = tid >> 7;
  const unsigned short* pA = Ahi + (size_t)(m0 + arow) * C_DIM + ap * 8;
  const float4* pB0 = reinterpret_cast<const float4*>(w_proj + (size_t)(j0 + brow) * C_DIM) + bp * 2;
  const float4* pB1 = pB0 + 4;

  f32x4 acc[2][4] = {};

  uint4 ra = *reinterpret_cast<const uint4*>(pA);
  float4 f0a = pB0[0], f0b = pB0[1];
  float4 f1a = pB1[0], f1b = pB1[1];
  *reinterpret_cast<uint4*>(&As[ap * 512 + arow * 8]) = ra;
  *reinterpret_cast<uint4*>(&Bs[bp * 1024 + brow * 8]) =
      make_uint4(pkbf(f0a.x, f0a.y), pkbf(f0a.z, f0a.w), pkbf(f0b.x, f0b.y), pkbf(f0b.z, f0b.w));
  *reinterpret_cast<uint4*>(&Bs[(bp + 2) * 1024 + brow * 8]) =
      make_uint4(pkbf(f1a.x, f1a.y), pkbf(f1a.z, f1a.w), pkbf(f1b.x, f1b.y), pkbf(f1b.z, f1b.w));
  __syncthreads();

  int cur = 0;
#pragma unroll
  for (int it = 0; it < 16; it++) {
    if (it < 15) {
      int k = (it + 1) * 32;
      int k4 = (it + 1) * 8;
      ra = *reinterpret_cast<const uint4*>(pA + k);
      f0a = pB0[k4]; f0b = pB0[k4 + 1];
      f1a = pB1[k4]; f1b = pB1[k4 + 1];
    }
    frag16 a_h[2], b_h[4];
#pragma unroll
    for (int i = 0; i < 2; i++)
      a_h[i] = *reinterpret_cast<const frag16*>(&As[cur * 2048 + qd * 512 + (rh * 32 + i * 16 + ln) * 8]);
#pragma unroll
    for (int j = 0; j < 4; j++)
      b_h[j] = *reinterpret_cast<const frag16*>(&Bs[cur * 4096 + qd * 1024 + (ch * 64 + j * 16 + ln) * 8]);
#pragma unroll
    for (int i = 0; i < 2; i++)
#pragma unroll
      for (int j = 0; j < 4; j++)
        acc[i][j] = __builtin_amdgcn_mfma_f32_16x16x32_bf16(a_h[i], b_h[j], acc[i][j], 0, 0, 0);
    if (it < 15) {
      int nxt = cur ^ 1;
      *reinterpret_cast<uint4*>(&As[nxt * 2048 + ap * 512 + arow * 8]) = ra;
      *reinterpret_cast<uint4*>(&Bs[nxt * 4096 + bp * 1024 + brow * 8]) =
          make_uint4(pkbf(f0a.x, f0a.y), pkbf(f0a.z, f0a.w), pkbf(f0b.x, f0b.y), pkbf(f0b.z, f0b.w));
      *reinterpret_cast<uint4*>(&Bs[nxt * 4096 + (bp + 2) * 1024 + brow * 8]) =
          make_uint4(pkbf(f1a.x, f1a.y), pkbf(f1a.z, f1a.w), pkbf(f1b.x, f1b.y), pkbf(f1b.z, f1b.w));
      __syncthreads();
      cur = nxt;
    }
  }

  float* sh32 = reinterpret_cast<float*>(pool);  // 64 x 68
#pragma unroll
  for (int chp = 0; chp < 2; chp++) {
    __syncthreads();
    if (ch == chp) {
#pragma unroll
      for (int i = 0; i < 2; i++)
#pragma unroll
        for (int j = 0; j < 4; j++) {
          int jcol = j * 16 + ln;
          float bv = bias[j0 + chp * 64 + jcol];
#pragma unroll
          for (int r = 0; r < 4; r++)
            sh32[(rh * 32 + i * 16 + qd * 4 + r) * 68 + jcol] = acc[i][j][r] + bv;
        }
    }
    __syncthreads();
#pragma unroll
    for (int p = 0; p < 4; p++) {
      int u = tid + p * 256;
      int row = u >> 4, c4 = (u & 15) * 4;
      *reinterpret_cast<float4*>(out + (size_t)(m0 + row) * C_DIM + j0 + chp * 64 + c4) =
          *reinterpret_cast<const float4*>(&sh32[row * 68 + c4]);
    }
  }
}

// ---------------------------------------------------------------------------
extern "C" void kernel_launch(void* const* d_in, const int* in_sizes, int n_in,
                              void* d_out, int out_size, void* d_ws, size_t ws_size,
                              hipStream_t stream) {
  const float* x = (const float*)d_in[0];
  const float* w_qkv = (const float*)d_in[1];
  const float* b_qkv = (const float*)d_in[2];
  const float* w_proj = (const float*)d_in[3];
  const float* b_proj = (const float*)d_in[4];
  const int* keyframes = (const int*)d_in[5];
  const int* clusters = (const int*)d_in[6];
  float* out = (float*)d_out;
  float* ws = (float*)d_ws;

  unsigned short* qhi = (unsigned short*)(ws + WS_QHI);
  unsigned short* khi = (unsigned short*)(ws + WS_KHI);
  unsigned short* vhi = (unsigned short*)(ws + WS_VHI);
  unsigned short* xahi = (unsigned short*)(ws + WS_XAHI);
  float* xbarp = ws + WS_XBARP;
  float* qbar = ws + WS_QBAR;
  float* g = ws + WS_G;
  float* agg = ws + WS_AGG;
  int* topkp = (int*)(ws + WS_TOPK);

  // 1. QKV GEMM (staging cvt, no prep dependency)
  gemm_qkv<<<768, 256, 0, stream>>>(x, w_qkv, b_qkv, qhi, khi, vhi);
  // 2. ranking chain (fp32, split launches — each kernel keeps its own
  //    register profile; grid-barrier and role-fusion variants both lost)
  xbar_part<<<64, 256, 0, stream>>>(x, keyframes, xbarp);
  qbar_k<<<32, 256, 0, stream>>>(w_qkv, b_qkv, xbarp, qbar);
  g_full<<<32, 256, 0, stream>>>(w_qkv, qbar, g);
  agg2_kernel<<<2048, 256, 0, stream>>>(x, g, agg);
  topk_kernel<<<4, 256, 0, stream>>>(agg, topkp);
  // 3. fused MFMA attention
  flash_mfma<<<dim3(MPC / 128, KCLUST, NH), 256, 0, stream>>>(
      qhi, khi, vhi, topkp, clusters, xahi);
  // 4. projection GEMM
  gemm_proj<<<512, 256, 0, stream>>>(xahi, w_proj, b_proj, out);
}

// Round 16
// 212.167 us; speedup vs baseline: 1.3138x; 1.0626x over previous
//
#include <hip/hip_runtime.h>
#include <hip/hip_bf16.h>

#define N_TOK 8192
#define C_DIM 512
#define NH 8
#define DH 64
#define KCLUST 4
#define TPF 512
#define TOPK 204
#define MPC 2048

// ---- workspace layout (float offsets) ----
#define WS_WQH    0            // w_qkv bf16: 786432 shorts = 393216 floats
#define WS_WPH    393216       // w_proj bf16: 262144 shorts = 131072 floats
#define WS_QHI    524288       // q hi (pre-scaled 0.125): 4194304 shorts
#define WS_KHI    2621440
#define WS_VHI    4718592
#define WS_XAHI   6815744      // xattn hi
#define WS_XBARP  8912896      // 4*16*512
#define WS_QBAR   8945664      // 32*64
#define WS_G      8947712      // 4*512
#define WS_AGG    8949760      // 4*8192
#define WS_TOPK   8982528      // ints 4*204

using frag16 = __attribute__((ext_vector_type(8))) short;
using f32x4  = __attribute__((ext_vector_type(4))) float;

__device__ __forceinline__ unsigned short f2bf(float x) {
  unsigned u = __float_as_uint(x);
  return (unsigned short)((u + 0x7fffu + ((u >> 16) & 1u)) >> 16);
}
__device__ __forceinline__ float bf2f(unsigned short h) {
  return __uint_as_float(((unsigned)h) << 16);
}
// packed RNE cvt of 2 floats -> 2 bf16 bit-patterns (v_cvt_pk_bf16_f32)
__device__ __forceinline__ unsigned pkbf(float a, float b) {
  __hip_bfloat162 t = __float22bfloat162_rn(make_float2(a, b));
  return *reinterpret_cast<unsigned*>(&t);
}

// ---------------------------------------------------------------------------
// prep (R11-validated): weight conversions + xbar partials. 1088 blocks.
//   [0,768)      w_qkv -> bf16
//   [768,1024)   w_proj -> bf16
//   [1024,1088)  xbar partials
// ---------------------------------------------------------------------------
__global__ __launch_bounds__(256) void prep(
    const float* __restrict__ w_qkv, const float* __restrict__ w_proj,
    const float* __restrict__ x, const int* __restrict__ keyframes,
    unsigned short* __restrict__ wqh, unsigned short* __restrict__ wph,
    float* __restrict__ xbarp) {
  const int bx = blockIdx.x, tid = threadIdx.x;
  if (bx < 1024) {
    const float* src = (bx < 768) ? w_qkv : w_proj;
    unsigned short* dst = (bx < 768) ? wqh : wph;
    int i = ((bx < 768) ? bx : (bx - 768)) * 256 + tid;
    float4 v = reinterpret_cast<const float4*>(src)[i];
    reinterpret_cast<uint2*>(dst)[i] = make_uint2(pkbf(v.x, v.y), pkbf(v.z, v.w));
  } else {
    int b = bx - 1024, kk = b >> 4, s = b & 15;
    int base = keyframes[kk] * TPF + s * 32;
    float a0 = 0.f, a1 = 0.f;
    for (int t = 0; t < 32; t++) {
      a0 += x[(size_t)(base + t) * C_DIM + tid];
      a1 += x[(size_t)(base + t) * C_DIM + tid + 256];
    }
    xbarp[(kk * 16 + s) * C_DIM + tid] = a0;
    xbarp[(kk * 16 + s) * C_DIM + tid + 256] = a1;
  }
}

// ---------------------------------------------------------------------------
// QKV GEMM (R11-validated): 128x128 tile, 1-pass bf16; A = x fp32 cvt in
// staging, B = wqh bf16 (uint4 copy). Reg-staged LDS dbuf, ONE barrier per
// K-iter, bank-skewed panels (1032), XCD swizzle, transpose epilogue.
// ---------------------------------------------------------------------------
#define APAN 1032
#define BUFS 8256
__global__ __launch_bounds__(256) void gemm_qkv(
    const float* __restrict__ x, const unsigned short* __restrict__ Bhi,
    const float* __restrict__ bias,
    unsigned short* __restrict__ qhi, unsigned short* __restrict__ khi,
    unsigned short* __restrict__ vhi) {
  __shared__ short pool[17408];
  const int tid = threadIdx.x;
  const int bid = blockIdx.x;
  const int grp = bid / 96;
  const int rem = bid - grp * 96;
  const int jblk = rem >> 3;
  const int m_idx = grp * 8 + (rem & 7);
  const int j0 = jblk * 128;
  const int m0 = m_idx * 128;
  const int wave = tid >> 6, lane = tid & 63;
  const int wr = wave >> 1, wc = wave & 1;
  const int qd = lane >> 4, ln = lane & 15;

  const int r0 = tid >> 2, p0 = tid & 3;
  const int r1 = r0 + 64;
  const float4* pA0 = reinterpret_cast<const float4*>(x + (size_t)(m0 + r0) * C_DIM) + p0 * 2;
  const float4* pA1 = reinterpret_cast<const float4*>(x + (size_t)(m0 + r1) * C_DIM) + p0 * 2;
  const unsigned short* pB0 = Bhi + (size_t)(j0 + r0) * C_DIM + p0 * 8;
  const unsigned short* pB1 = Bhi + (size_t)(j0 + r1) * C_DIM + p0 * 8;

  f32x4 acc[4][4] = {};

  float4 fa[4];
  uint4 rb[2];
  fa[0] = pA0[0]; fa[1] = pA0[1];
  fa[2] = pA1[0]; fa[3] = pA1[1];
  rb[0] = *reinterpret_cast<const uint4*>(pB0);
  rb[1] = *reinterpret_cast<const uint4*>(pB1);

  // prologue: cvt + write k-slab 0 into buf 0
  {
    *reinterpret_cast<uint4*>(&pool[p0 * APAN + r0 * 8]) =
        make_uint4(pkbf(fa[0].x, fa[0].y), pkbf(fa[0].z, fa[0].w),
                   pkbf(fa[1].x, fa[1].y), pkbf(fa[1].z, fa[1].w));
    *reinterpret_cast<uint4*>(&pool[p0 * APAN + r1 * 8]) =
        make_uint4(pkbf(fa[2].x, fa[2].y), pkbf(fa[2].z, fa[2].w),
                   pkbf(fa[3].x, fa[3].y), pkbf(fa[3].z, fa[3].w));
    *reinterpret_cast<uint4*>(&pool[4 * APAN + p0 * APAN + r0 * 8]) = rb[0];
    *reinterpret_cast<uint4*>(&pool[4 * APAN + p0 * APAN + r1 * 8]) = rb[1];
  }
  __syncthreads();

  int cur = 0;
#pragma unroll
  for (int it = 0; it < 16; it++) {
    if (it < 15) {  // issue next k-slab loads (hidden under MFMAs)
      int k4 = (it + 1) * 8;
      fa[0] = pA0[k4]; fa[1] = pA0[k4 + 1];
      fa[2] = pA1[k4]; fa[3] = pA1[k4 + 1];
      rb[0] = *reinterpret_cast<const uint4*>(pB0 + (it + 1) * 32);
      rb[1] = *reinterpret_cast<const uint4*>(pB1 + (it + 1) * 32);
    }
    const int bb = cur * BUFS;
    frag16 a_h[4], b_h[4];
#pragma unroll
    for (int i = 0; i < 4; i++) {
      int row = wr * 64 + i * 16 + ln;
      a_h[i] = *reinterpret_cast<const frag16*>(&pool[bb + qd * APAN + row * 8]);
    }
#pragma unroll
    for (int j = 0; j < 4; j++) {
      int row = wc * 64 + j * 16 + ln;
      b_h[j] = *reinterpret_cast<const frag16*>(&pool[bb + 4 * APAN + qd * APAN + row * 8]);
    }
#pragma unroll
    for (int i = 0; i < 4; i++)
#pragma unroll
      for (int j = 0; j < 4; j++)
        acc[i][j] = __builtin_amdgcn_mfma_f32_16x16x32_bf16(a_h[i], b_h[j], acc[i][j], 0, 0, 0);

    if (it < 15) {  // cvt + write next slab into the other buffer
      const int nb = (cur ^ 1) * BUFS;
      *reinterpret_cast<uint4*>(&pool[nb + p0 * APAN + r0 * 8]) =
          make_uint4(pkbf(fa[0].x, fa[0].y), pkbf(fa[0].z, fa[0].w),
                     pkbf(fa[1].x, fa[1].y), pkbf(fa[1].z, fa[1].w));
      *reinterpret_cast<uint4*>(&pool[nb + p0 * APAN + r1 * 8]) =
          make_uint4(pkbf(fa[2].x, fa[2].y), pkbf(fa[2].z, fa[2].w),
                     pkbf(fa[3].x, fa[3].y), pkbf(fa[3].z, fa[3].w));
      *reinterpret_cast<uint4*>(&pool[nb + 4 * APAN + p0 * APAN + r0 * 8]) = rb[0];
      *reinterpret_cast<uint4*>(&pool[nb + 4 * APAN + p0 * APAN + r1 * 8]) = rb[1];
    }
    __syncthreads();  // single barrier: flip buffers
    cur ^= 1;
  }

  // ---- epilogue: LDS transpose (128x136) -> coalesced line writes ----
  const int sel = j0 >> 9;
  const float qscale = (sel == 0) ? 0.125f : 1.0f;
  unsigned short* dst0 = (sel == 0) ? qhi : ((sel == 1) ? khi : vhi);
  short* sh = pool;

#pragma unroll
  for (int i = 0; i < 4; i++)
#pragma unroll
    for (int j = 0; j < 4; j++) {
      int jcol = wc * 64 + j * 16 + ln;
      float bv = bias[j0 + jcol];
#pragma unroll
      for (int r = 0; r < 4; r++) {
        int mrow = wr * 64 + i * 16 + qd * 4 + r;
        sh[mrow * 136 + jcol] = (short)f2bf((acc[i][j][r] + bv) * qscale);
      }
    }
  __syncthreads();
#pragma unroll
  for (int p = 0; p < 8; p++) {
    int u = tid + p * 256;
    int row = u >> 4, c = (u & 15) * 8;
    int hh = ((j0 + c) >> 6) & 7, d0 = c & 63;
    *reinterpret_cast<uint4*>(dst0 + ((size_t)hh * N_TOK + m0 + row) * DH + d0) =
        *reinterpret_cast<const uint4*>(&sh[row * 136 + c]);
  }
}

// ---------------------------------------------------------------------------
// qbar[h][kk][d] = W_q . mean(x over keyframe kk) + b_q  (R11-validated)
// ---------------------------------------------------------------------------
__global__ __launch_bounds__(256) void qbar_k(const float* __restrict__ w_qkv,
                                              const float* __restrict__ b_qkv,
                                              const float* __restrict__ xbarp,
                                              float* __restrict__ qbar) {
  __shared__ float xs[C_DIM];
  __shared__ float red[256];
  int blk = blockIdx.x, h = blk >> 2, kk = blk & 3, tid = threadIdx.x;
  for (int i = tid; i < C_DIM; i += 256) {
    float a = 0.f;
    for (int s = 0; s < 16; s++) a += xbarp[(kk * 16 + s) * C_DIM + i];
    xs[i] = a * (1.f / 512.f);
  }
  __syncthreads();
  int d = tid & 63, pp = tid >> 6;
  const float* wrow = w_qkv + (size_t)(h * 64 + d) * C_DIM + pp * 128;
  float a = 0.f;
  for (int c = 0; c < 128; c++) a += wrow[c] * xs[pp * 128 + c];
  red[tid] = a;
  __syncthreads();
  if (pp == 0)
    qbar[(h * 4 + kk) * 64 + d] = red[d] + red[64 + d] + red[128 + d] + red[192 + d] +
                                  b_qkv[h * 64 + d];
}

// ---------------------------------------------------------------------------
// g[kk][c] = sum_j qbar[kk][j] W_k[j][c]  (R11-validated)
// ---------------------------------------------------------------------------
__global__ __launch_bounds__(256) void g_full(const float* __restrict__ w_qkv,
                                              const float* __restrict__ qbar,
                                              float* __restrict__ g) {
  __shared__ float qs[C_DIM];
  __shared__ float red[256];
  int kk = blockIdx.x >> 3, cs = blockIdx.x & 7, tid = threadIdx.x;
  for (int i = tid; i < C_DIM; i += 256)
    qs[i] = qbar[((i >> 6) * 4 + kk) * 64 + (i & 63)];
  __syncthreads();
  int jg = tid >> 6, c = tid & 63;
  float a = 0.f;
  const float* wk = w_qkv + (size_t)C_DIM * C_DIM + cs * 64 + c;
  for (int j = jg * 128; j < jg * 128 + 128; j++)
    a += qs[j] * wk[(size_t)j * C_DIM];
  red[tid] = a;
  __syncthreads();
  if (jg == 0)
    g[kk * C_DIM + cs * 64 + c] = red[c] + red[64 + c] + red[128 + c] + red[192 + c];
}

// ---------------------------------------------------------------------------
// agg[kk][n] = g[kk] . x[n]  (R11-validated)
// ---------------------------------------------------------------------------
__global__ __launch_bounds__(256) void agg2_kernel(const float* __restrict__ x,
                                                   const float* __restrict__ g,
                                                   float* __restrict__ agg) {
  __shared__ float gs[KCLUST][C_DIM];
  int tid = threadIdx.x;
  for (int i = tid; i < KCLUST * C_DIM; i += 256) gs[i >> 9][i & 511] = g[i];
  __syncthreads();
  int wave = tid >> 6, lane = tid & 63;
  int n = blockIdx.x * 4 + wave;
  const float4* xp = reinterpret_cast<const float4*>(x + (size_t)n * C_DIM);
  float4 xa = xp[lane], xb = xp[lane + 64];
  float a[4];
#pragma unroll
  for (int kk = 0; kk < 4; kk++) {
    const float4* gpv = reinterpret_cast<const float4*>(&gs[kk][0]);
    float4 ga = gpv[lane], gb2 = gpv[lane + 64];
    a[kk] = xa.x * ga.x + xa.y * ga.y + xa.z * ga.z + xa.w * ga.w +
            xb.x * gb2.x + xb.y * gb2.y + xb.z * gb2.z + xb.w * gb2.w;
  }
#pragma unroll
  for (int off = 32; off >= 1; off >>= 1) {
    a[0] += __shfl_xor(a[0], off);
    a[1] += __shfl_xor(a[1], off);
    a[2] += __shfl_xor(a[2], off);
    a[3] += __shfl_xor(a[3], off);
  }
  if (lane == 0) {
    agg[0 * N_TOK + n] = a[0];
    agg[1 * N_TOK + n] = a[1];
    agg[2 * N_TOK + n] = a[2];
    agg[3 * N_TOK + n] = a[3];
  }
}

// ---------------------------------------------------------------------------
// Deterministic top-204: 8-bit histogram radix; scans via wave shuffles
// (cuts ~96 __syncthreads to ~18 on this 4-block serial-chain kernel).
// ---------------------------------------------------------------------------
__device__ __forceinline__ int block_scan_incl(int v, int* wsum, int tid) {
  int lane = tid & 63, wv = tid >> 6;
#pragma unroll
  for (int off = 1; off < 64; off <<= 1) {
    int t = __shfl_up(v, off, 64);
    if (lane >= off) v += t;
  }
  if (lane == 63) wsum[wv] = v;
  __syncthreads();
  if (wv > 0) v += wsum[0];
  if (wv > 1) v += wsum[1];
  if (wv > 2) v += wsum[2];
  __syncthreads();
  return v;
}

__global__ __launch_bounds__(256) void topk_kernel(const float* __restrict__ agg,
                                                   int* __restrict__ topk) {
  __shared__ unsigned sk[N_TOK];
  __shared__ int hist[256];
  __shared__ int scn[256];
  __shared__ int wsum[4];
  __shared__ int sel_bin, sel_rem;
  int kk = blockIdx.x, tid = threadIdx.x;
  const float* row = agg + (size_t)kk * N_TOK;

  for (int i = tid; i < N_TOK; i += 256) {
    unsigned u = __float_as_uint(row[i]);
    sk[i] = (u & 0x80000000u) ? ~u : (u | 0x80000000u);
  }
  __syncthreads();

  unsigned prefix = 0;
  int remaining = TOPK;
#pragma unroll
  for (int rnd = 3; rnd >= 0; rnd--) {
    int shift = rnd * 8;
    hist[tid] = 0;
    __syncthreads();
    for (int i = tid; i < N_TOK; i += 256) {
      unsigned key = sk[i];
      bool in = (rnd == 3) || ((key >> (shift + 8)) == prefix);
      if (in) atomicAdd(&hist[(key >> shift) & 255], 1);
    }
    __syncthreads();
    int sv = block_scan_incl(hist[255 - tid], wsum, tid);
    scn[tid] = sv;
    __syncthreads();
    int b = tid;
    int cgt = (b == 255) ? 0 : scn[254 - b];
    if (cgt < remaining && remaining <= cgt + hist[b]) {
      sel_bin = b;
      sel_rem = remaining - cgt;
    }
    __syncthreads();
    prefix = (prefix << 8) | (unsigned)sel_bin;
    remaining = sel_rem;
    __syncthreads();
  }
  unsigned kth = prefix;

  int* out_row = topk + kk * TOPK;
  int base = tid * 32;

  // pass A: strictly greater
  int cA = 0;
  for (int i = 0; i < 32; i++) cA += (sk[base + i] > kth) ? 1 : 0;
  int sA = block_scan_incl(cA, wsum, tid);
  scn[tid] = sA;
  __syncthreads();
  int exclA = sA - cA;
  int G = scn[255];
  int p = exclA;
  for (int i = 0; i < 32; i++)
    if (sk[base + i] > kth) out_row[p++] = base + i;
  __syncthreads();

  // pass B: equal (ties -> lowest index)
  int cB = 0;
  for (int i = 0; i < 32; i++) cB += (sk[base + i] == kth) ? 1 : 0;
  int sB = block_scan_incl(cB, wsum, tid);
  int exclB = sB - cB;
  int pos = G + exclB;
  for (int i = 0; i < 32; i++) {
    if (sk[base + i] == kth) {
      if (pos < TOPK) out_row[pos] = base + i;
      pos++;
    }
  }
}

// ---------------------------------------------------------------------------
// MFMA flash attention (R11-validated): 128 q/block, hi-only, 1-pass QK/PV.
// ---------------------------------------------------------------------------
__global__ __launch_bounds__(256) void flash_mfma(
    const unsigned short* __restrict__ qhi, const unsigned short* __restrict__ khi,
    const unsigned short* __restrict__ vhi, const int* __restrict__ topk,
    const int* __restrict__ clusters, unsigned short* __restrict__ xahi) {
  __shared__ short Ks[64 * 72];
  __shared__ short Vs[64 * 72];
  __shared__ short Ps[128 * 72];
  __shared__ int idx[TOPK];
  const int tid = threadIdx.x;
  const int qb = blockIdx.x, kk = blockIdx.y, h = blockIdx.z;
  const int wave = tid >> 6, lane = tid & 63;
  const int ln = lane & 15, qd = lane >> 4;

  for (int i = tid; i < TOPK; i += 256) idx[i] = topk[kk * TOPK + i];

  const int q_local0 = qb * 128;
  const int frame = clusters[kk * 4 + (q_local0 >> 9)];
  const int tokbase = frame * TPF + (q_local0 & 511);

  frag16 qa_h[2][2];
#pragma unroll
  for (int mt = 0; mt < 2; mt++) {
    const int tok_m = tokbase + wave * 32 + mt * 16 + ln;
    const unsigned short* qr_h = qhi + ((size_t)h * N_TOK + tok_m) * DH;
#pragma unroll
    for (int s = 0; s < 2; s++)
      qa_h[mt][s] = *reinterpret_cast<const frag16*>(qr_h + s * 32 + qd * 8);
  }

  f32x4 acc_o[2][4] = {};
  float lsum[2][4] = {};

  __syncthreads();

  for (int t0 = 0; t0 < TOPK; t0 += 64) {
#pragma unroll
    for (int i = 0; i < 2; i++) {
      int u = tid + i * 256;
      int r = u >> 3, oct = u & 7;
      int t = t0 + r;
      if (t > TOPK - 1) t = TOPK - 1;
      *reinterpret_cast<frag16*>(&Ks[r * 72 + oct * 8]) =
          *reinterpret_cast<const frag16*>(khi + ((size_t)h * N_TOK + idx[t]) * DH + oct * 8);
    }
    {
      int tk = (tid & 15) * 4, td = (tid >> 4) * 4;
      uint2 w2[4];
#pragma unroll
      for (int i = 0; i < 4; i++) {
        int t = t0 + tk + i;
        if (t > TOPK - 1) t = TOPK - 1;
        w2[i] = *reinterpret_cast<const uint2*>(vhi + ((size_t)h * N_TOK + idx[t]) * DH + td);
      }
#pragma unroll
      for (int dd = 0; dd < 4; dd++) {
        unsigned s0 = (dd < 2) ? (w2[0].x >> (16 * dd)) : (w2[0].y >> (16 * (dd - 2)));
        unsigned s1 = (dd < 2) ? (w2[1].x >> (16 * dd)) : (w2[1].y >> (16 * (dd - 2)));
        unsigned s2 = (dd < 2) ? (w2[2].x >> (16 * dd)) : (w2[2].y >> (16 * (dd - 2)));
        unsigned s3 = (dd < 2) ? (w2[3].x >> (16 * dd)) : (w2[3].y >> (16 * (dd - 2)));
        *reinterpret_cast<uint2*>(&Vs[(td + dd) * 72 + tk]) =
            make_uint2((s0 & 0xffffu) | (s1 << 16), (s2 & 0xffffu) | (s3 << 16));
      }
    }
    __syncthreads();

#pragma unroll
    for (int mt = 0; mt < 2; mt++) {
      f32x4 sacc[4] = {};
#pragma unroll
      for (int c = 0; c < 4; c++) {
#pragma unroll
        for (int s = 0; s < 2; s++) {
          frag16 bh = *reinterpret_cast<const frag16*>(&Ks[(c * 16 + ln) * 72 + s * 32 + qd * 8]);
          sacc[c] = __builtin_amdgcn_mfma_f32_16x16x32_bf16(qa_h[mt][s], bh, sacc[c], 0, 0, 0);
        }
      }
#pragma unroll
      for (int c = 0; c < 4; c++) {
#pragma unroll
        for (int r = 0; r < 4; r++) {
          int tg = t0 + c * 16 + ln;
          float p = (tg < TOPK) ? __expf(sacc[c][r]) : 0.f;
          lsum[mt][r] += p;
          Ps[(wave * 32 + mt * 16 + qd * 4 + r) * 72 + c * 16 + ln] = (short)f2bf(p);
        }
      }
    }

#pragma unroll
    for (int mt = 0; mt < 2; mt++)
#pragma unroll
      for (int s = 0; s < 2; s++) {
        frag16 pa = *reinterpret_cast<const frag16*>(
            &Ps[(wave * 32 + mt * 16 + ln) * 72 + s * 32 + qd * 8]);
#pragma unroll
        for (int dt = 0; dt < 4; dt++) {
          frag16 vb = *reinterpret_cast<const frag16*>(&Vs[(dt * 16 + ln) * 72 + s * 32 + qd * 8]);
          acc_o[mt][dt] = __builtin_amdgcn_mfma_f32_16x16x32_bf16(pa, vb, acc_o[mt][dt], 0, 0, 0);
        }
      }
    __syncthreads();
  }

#pragma unroll
  for (int mt = 0; mt < 2; mt++)
#pragma unroll
    for (int r = 0; r < 4; r++) {
      float l = lsum[mt][r];
      l += __shfl_xor(l, 1);
      l += __shfl_xor(l, 2);
      l += __shfl_xor(l, 4);
      l += __shfl_xor(l, 8);
      lsum[mt][r] = 1.f / l;
    }

#pragma unroll
  for (int mt = 0; mt < 2; mt++)
#pragma unroll
    for (int dt = 0; dt < 4; dt++)
#pragma unroll
      for (int r = 0; r < 4; r++)
        Ps[(wave * 32 + mt * 16 + qd * 4 + r) * 72 + dt * 16 + ln] =
            (short)f2bf(acc_o[mt][dt][r] * lsum[mt][r]);
  __syncthreads();
#pragma unroll
  for (int p = 0; p < 4; p++) {
    int u = tid + p * 256;
    int row = u >> 3, c = (u & 7) * 8;
    *reinterpret_cast<uint4*>(xahi + (size_t)(tokbase + row) * C_DIM + h * DH + c) =
        *reinterpret_cast<const uint4*>(&Ps[row * 72 + c]);
  }
}

// ---------------------------------------------------------------------------
// Projection GEMM (R11-validated): 64x128, reg-dbuf pipeline, B = wph bf16,
// swizzle, fp32 LDS-transpose epilogue.
// ---------------------------------------------------------------------------
__global__ __launch_bounds__(256) void gemm_proj(
    const unsigned short* __restrict__ Ahi, const unsigned short* __restrict__ Bhi,
    const float* __restrict__ bias, float* __restrict__ out) {
  __shared__ short pool[12288];
  short* As = pool;
  short* Bs = pool + 4096;
  const int tid = threadIdx.x;
  const int bid = blockIdx.x;
  const int grp = bid / 32;
  const int rem = bid - grp * 32;
  const int jblk = rem >> 3;
  const int m_idx = grp * 8 + (rem & 7);
  const int j0 = jblk * 128;
  const int m0 = m_idx * 64;
  const int wave = tid >> 6, lane = tid & 63;
  const int rh = wave >> 1, ch = wave & 1;
  const int qd = lane >> 4, ln = lane & 15;

  const int arow = tid & 63, ap = tid >> 6;
  const int brow = tid & 127, bp = tid >> 7;
  const unsigned short* pA = Ahi + (size_t)(m0 + arow) * C_DIM + ap * 8;
  const unsigned short* pB0 = Bhi + (size_t)(j0 + brow) * C_DIM + bp * 8;
  const unsigned short* pB1 = pB0 + 16;

  f32x4 acc[2][4] = {};

  uint4 ra = *reinterpret_cast<const uint4*>(pA);
  uint4 rb0 = *reinterpret_cast<const uint4*>(pB0);
  uint4 rb1 = *reinterpret_cast<const uint4*>(pB1);
  *reinterpret_cast<uint4*>(&As[ap * 512 + arow * 8]) = ra;
  *reinterpret_cast<uint4*>(&Bs[bp * 1024 + brow * 8]) = rb0;
  *reinterpret_cast<uint4*>(&Bs[(bp + 2) * 1024 + brow * 8]) = rb1;
  __syncthreads();

  int cur = 0;
#pragma unroll
  for (int it = 0; it < 16; it++) {
    if (it < 15) {
      int k = (it + 1) * 32;
      ra = *reinterpret_cast<const uint4*>(pA + k);
      rb0 = *reinterpret_cast<const uint4*>(pB0 + k);
      rb1 = *reinterpret_cast<const uint4*>(pB1 + k);
    }
    frag16 a_h[2], b_h[4];
#pragma unroll
    for (int i = 0; i < 2; i++)
      a_h[i] = *reinterpret_cast<const frag16*>(&As[cur * 2048 + qd * 512 + (rh * 32 + i * 16 + ln) * 8]);
#pragma unroll
    for (int j = 0; j < 4; j++)
      b_h[j] = *reinterpret_cast<const frag16*>(&Bs[cur * 4096 + qd * 1024 + (ch * 64 + j * 16 + ln) * 8]);
#pragma unroll
    for (int i = 0; i < 2; i++)
#pragma unroll
      for (int j = 0; j < 4; j++)
        acc[i][j] = __builtin_amdgcn_mfma_f32_16x16x32_bf16(a_h[i], b_h[j], acc[i][j], 0, 0, 0);
    if (it < 15) {
      int nxt = cur ^ 1;
      *reinterpret_cast<uint4*>(&As[nxt * 2048 + ap * 512 + arow * 8]) = ra;
      *reinterpret_cast<uint4*>(&Bs[nxt * 4096 + bp * 1024 + brow * 8]) = rb0;
      *reinterpret_cast<uint4*>(&Bs[nxt * 4096 + (bp + 2) * 1024 + brow * 8]) = rb1;
      __syncthreads();
      cur = nxt;
    }
  }

  float* sh32 = reinterpret_cast<float*>(pool);  // 64 x 68
#pragma unroll
  for (int chp = 0; chp < 2; chp++) {
    __syncthreads();
    if (ch == chp) {
#pragma unroll
      for (int i = 0; i < 2; i++)
#pragma unroll
        for (int j = 0; j < 4; j++) {
          int jcol = j * 16 + ln;
          float bv = bias[j0 + chp * 64 + jcol];
#pragma unroll
          for (int r = 0; r < 4; r++)
            sh32[(rh * 32 + i * 16 + qd * 4 + r) * 68 + jcol] = acc[i][j][r] + bv;
        }
    }
    __syncthreads();
#pragma unroll
    for (int p = 0; p < 4; p++) {
      int u = tid + p * 256;
      int row = u >> 4, c4 = (u & 15) * 4;
      *reinterpret_cast<float4*>(out + (size_t)(m0 + row) * C_DIM + j0 + chp * 64 + c4) =
          *reinterpret_cast<const float4*>(&sh32[row * 68 + c4]);
    }
  }
}

// ---------------------------------------------------------------------------
extern "C" void kernel_launch(void* const* d_in, const int* in_sizes, int n_in,
                              void* d_out, int out_size, void* d_ws, size_t ws_size,
                              hipStream_t stream) {
  const float* x = (const float*)d_in[0];
  const float* w_qkv = (const float*)d_in[1];
  const float* b_qkv = (const float*)d_in[2];
  const float* w_proj = (const float*)d_in[3];
  const float* b_proj = (const float*)d_in[4];
  const int* keyframes = (const int*)d_in[5];
  const int* clusters = (const int*)d_in[6];
  float* out = (float*)d_out;
  float* ws = (float*)d_ws;

  unsigned short* wqh = (unsigned short*)(ws + WS_WQH);
  unsigned short* wph = (unsigned short*)(ws + WS_WPH);
  unsigned short* qhi = (unsigned short*)(ws + WS_QHI);
  unsigned short* khi = (unsigned short*)(ws + WS_KHI);
  unsigned short* vhi = (unsigned short*)(ws + WS_VHI);
  unsigned short* xahi = (unsigned short*)(ws + WS_XAHI);
  float* xbarp = ws + WS_XBARP;
  float* qbar = ws + WS_QBAR;
  float* g = ws + WS_G;
  float* agg = ws + WS_AGG;
  int* topkp = (int*)(ws + WS_TOPK);

  // 1. weight cvt + xbar partials (one parallel launch)
  prep<<<1088, 256, 0, stream>>>(w_qkv, w_proj, x, keyframes, wqh, wph, xbarp);
  // 2. QKV GEMM (A fp32 cvt-in-staging, B bf16 pre-cvt — measured best combo)
  gemm_qkv<<<768, 256, 0, stream>>>(x, wqh, b_qkv, qhi, khi, vhi);
  // 3. ranking chain (fp32, deterministic, split launches)
  qbar_k<<<32, 256, 0, stream>>>(w_qkv, b_qkv, xbarp, qbar);
  g_full<<<32, 256, 0, stream>>>(w_qkv, qbar, g);
  agg2_kernel<<<2048, 256, 0, stream>>>(x, g, agg);
  topk_kernel<<<4, 256, 0, stream>>>(agg, topkp);
  // 4. fused MFMA attention
  flash_mfma<<<dim3(MPC / 128, KCLUST, NH), 256, 0, stream>>>(
      qhi, khi, vhi, topkp, clusters, xahi);
  // 5. projection GEMM
  gemm_proj<<<512, 256, 0, stream>>>(xahi, wph, b_proj, out);
}